// Round 8
// baseline (399.577 us; speedup 1.0000x reference)
//
#include <hip/hip_runtime.h>
#include <hip/hip_bf16.h>
#include <math.h>

#define N_NODES 4096
#define C_DIM   384
#define B_DIM   8
#define K_NB    8
#define E_TOT   (N_NODES * K_NB)     // 32768
#define M_ROWS  (B_DIM * N_NODES)    // 32768
#define NCHUNK  25                   // one chunk per 16-slot window tile

typedef unsigned long long u64;
typedef unsigned short u16;
typedef __attribute__((ext_vector_type(8))) short bf16x8;
typedef __attribute__((ext_vector_type(4))) float f32x4;
#define KEY_INF 0xFFFFFFFFFFFFFFFFull

__device__ __forceinline__ u16 f2bf(float f) {
  unsigned u = __float_as_uint(f);
  u += 0x7FFFu + ((u >> 16) & 1u);
  return (u16)(u >> 16);
}
__device__ __forceinline__ float bf2f(u16 h) {
  return __uint_as_float((unsigned)h << 16);
}
__device__ __forceinline__ f32x4 mfma16(bf16x8 a, bf16x8 b, f32x4 c) {
  return __builtin_amdgcn_mfma_f32_16x16x32_bf16(a, b, c, 0, 0, 0);
}

__device__ __forceinline__ void ce(u64& a, u64& b) {
  u64 lo = a < b ? a : b;
  u64 hi = a < b ? b : a;
  a = lo; b = hi;
}
__device__ __forceinline__ void ins8(u64 key, u64 (&r)[8]) {
  if (key < r[7]) {
    #pragma unroll
    for (int i = 0; i < 8; i++) {
      u64 lo = key < r[i] ? key : r[i];
      u64 hi = key < r[i] ? r[i] : key;
      r[i] = lo; key = hi;
    }
  }
}
// merge two ascending sorted-8 lists -> ascending 8 smallest
__device__ __forceinline__ void merge8(u64 (&r)[8], const u64 (&o)[8]) {
  u64 c[8];
  #pragma unroll
  for (int i = 0; i < 8; i++) c[i] = r[i] < o[7 - i] ? r[i] : o[7 - i];
  ce(c[0], c[4]); ce(c[1], c[5]); ce(c[2], c[6]); ce(c[3], c[7]);
  ce(c[0], c[2]); ce(c[1], c[3]); ce(c[4], c[6]); ce(c[5], c[7]);
  ce(c[0], c[1]); ce(c[2], c[3]); ce(c[4], c[5]); ce(c[6], c[7]);
  #pragma unroll
  for (int i = 0; i < 8; i++) r[i] = c[i];
}

// ---------------- weight prep: transpose + bf16 ----------------
__global__ __launch_bounds__(256) void k_prep_w(
    const float* __restrict__ W1, const float* __restrict__ W2,
    const float* __restrict__ W3, const float* __restrict__ U1,
    const float* __restrict__ U2,
    u16* __restrict__ Wt1, u16* __restrict__ Wt2, u16* __restrict__ Wt3,
    u16* __restrict__ U1t, u16* __restrict__ U2t) {
  int idx = blockIdx.x * 256 + threadIdx.x;
  if (idx < 147456) {
    int n = idx / 384, k = idx % 384;
    Wt1[idx] = f2bf(W1[k * 384 + n]);
  } else if (idx < 294912) {
    int i = idx - 147456; int n = i / 384, k = i % 384;
    Wt2[i] = f2bf(W2[k * 384 + n]);
  } else if (idx < 442368) {
    int i = idx - 294912; int n = i / 384, k = i % 384;
    Wt3[i] = f2bf(W3[k * 384 + n]);
  } else if (idx < 516096) {
    int i = idx - 442368; int n = i / 384, k = i % 384;
    U1t[i] = f2bf(U1[k * 192 + n]);
  } else if (idx < 534528) {
    int i = idx - 516096; int n = i / 192, k = i % 192;
    U2t[i] = f2bf(U2[k * 96 + n]);
  }
}

// ---------------- transpose + batch mean -> Xb (bf16) + fh/fl ----------------
__global__ __launch_bounds__(256) void k_transpose_mean(
    const float* __restrict__ fea, u16* __restrict__ Xb,
    u16* __restrict__ fh, u16* __restrict__ fl) {
  __shared__ float tb[32][132];
  __shared__ float ac[32][132];
  int n0 = blockIdx.x * 128, c0 = blockIdx.y * 32;
  int tx = threadIdx.x, ty = threadIdx.y;   // (32,8)
  for (int i = ty; i < 32; i += 8) {
    #pragma unroll
    for (int e = 0; e < 4; e++) ac[i][tx * 4 + e] = 0.0f;
  }
  __syncthreads();
  for (int b = 0; b < B_DIM; b++) {
    for (int i = ty; i < 32; i += 8) {
      float4 v = *(const float4*)(fea +
          ((size_t)b * C_DIM + (c0 + i)) * N_NODES + n0 + tx * 4);
      *(float4*)&tb[i][tx * 4] = v;
      ac[i][tx * 4 + 0] += v.x;
      ac[i][tx * 4 + 1] += v.y;
      ac[i][tx * 4 + 2] += v.z;
      ac[i][tx * 4 + 3] += v.w;
    }
    __syncthreads();
    for (int rr = ty; rr < 128; rr += 8) {
      size_t o = ((size_t)b * N_NODES + (n0 + rr)) * C_DIM + c0 + tx;
      Xb[o] = f2bf(tb[tx][rr]);
    }
    __syncthreads();
  }
  for (int rr = ty; rr < 128; rr += 8) {
    float m = ac[tx][rr] * 0.125f;
    u16 h = f2bf(m);
    size_t o = (size_t)(n0 + rr) * C_DIM + c0 + tx;
    fh[o] = h;
    fl[o] = f2bf(m - bf2f(h));
  }
}

// ---------------- squared norms (from hi+lo) ----------------
__global__ __launch_bounds__(64) void k_x2(const u16* __restrict__ fh,
                                           const u16* __restrict__ fl,
                                           float* __restrict__ x2) {
  int n = blockIdx.x;
  int lane = threadIdx.x;
  const u16* rh = fh + (size_t)n * C_DIM;
  const u16* rl = fl + (size_t)n * C_DIM;
  float s = 0.0f;
  for (int c = lane; c < C_DIM; c += 64) {
    float v = bf2f(rh[c]) + bf2f(rl[c]);
    s += v * v;
  }
  for (int d = 32; d > 0; d >>= 1) s += __shfl_down(s, d);
  if (lane == 0) x2[n] = s;
}

// ---------------- windowed distance + top-8, one 16x16 tile per wave ----------------
// comb >= 0.7*sd so any j at grid-distance >= 9 has comb >= 6.3; each 4x4 patch
// scans its 20x20 window = 400 slots = 25 tiles of 16. Wave handles ONE tile:
// 12 k-steps x 4 loads, 36 MFMA, then a cross-lane bitonic sort-16 per row
// yields the ascending top-8 directly (lanes 0-7 write). 6400 waves total.
__global__ __launch_bounds__(256) void k_dist_win(
    const u16* __restrict__ fh, const u16* __restrict__ fl,
    const float* __restrict__ x2, u64* __restrict__ pk) {
  int t = threadIdx.x;
  int lane = t & 63, w = t >> 6;
  int id = blockIdx.x * 4 + w;           // 0..6399
  int p = id / 25, c = id - p * 25;      // patch, chunk(tile)
  int py = p >> 4, px = p & 15;          // 16x16 patch grid
  int iy0 = py * 4, ix0 = px * 4;
  int l15 = lane & 15;
  int kb = (lane >> 4) * 8;

  // A rows = the 16 patch nodes
  int arow = (iy0 + (l15 >> 2)) * 64 + (ix0 + (l15 & 3));
  const u16* ah = fh + (size_t)arow * C_DIM + kb;
  const u16* al = fl + (size_t)arow * C_DIM + kb;

  // B slot for this lane: s = c*16 + l15 in the 20x20 window
  int s = c * 16 + l15;
  int sy = s / 20, sx = s - sy * 20;
  int jy = iy0 - 8 + sy, jx = ix0 - 8 + sx;
  bool valid = ((unsigned)jy < 64u) && ((unsigned)jx < 64u);
  int j = jy * 64 + jx;
  int jc = valid ? j : 0;
  const u16* bh = fh + (size_t)jc * C_DIM + kb;
  const u16* bl = fl + (size_t)jc * C_DIM + kb;

  f32x4 acc = {0.f, 0.f, 0.f, 0.f};
  #pragma unroll
  for (int kk = 0; kk < C_DIM; kk += 32) {
    bf16x8 a_h = *(const bf16x8*)(ah + kk);
    bf16x8 a_l = *(const bf16x8*)(al + kk);
    bf16x8 b_h = *(const bf16x8*)(bh + kk);
    bf16x8 b_l = *(const bf16x8*)(bl + kk);
    acc = mfma16(a_h, b_h, acc);
    acc = mfma16(a_l, b_h, acc);
    acc = mfma16(a_h, b_l, acc);
  }

  float x2j = valid ? x2[j] : 0.0f;
  #pragma unroll
  for (int r = 0; r < 4; r++) {
    int r16 = ((lane >> 4) << 2) + r;
    int iy = iy0 + (r16 >> 2), ix = ix0 + (r16 & 3);
    int i = iy * 64 + ix;
    float x2i = x2[i];
    float d2 = x2i + x2j - 2.0f * acc[r];
    float fd = sqrtf(fmaxf(d2, 0.0f));
    float dy = (float)(iy - jy), dx = (float)(ix - jx);
    float sd = sqrtf(dy * dy + dx * dx);
    float comb = 0.7f * sd + 0.3f * fd;
    u64 key = valid ? (((u64)__float_as_uint(comb) << 12) | (u64)j) : KEY_INF;
    // bitonic sort-16 across the 16 lanes of this group (ascending by l15)
    #pragma unroll
    for (int k2 = 2; k2 <= 16; k2 <<= 1) {
      #pragma unroll
      for (int m2 = k2 >> 1; m2 > 0; m2 >>= 1) {
        u64 o = __shfl_xor(key, m2);
        bool up = ((l15 & k2) == 0);
        bool low = ((l15 & m2) == 0);
        u64 mn = key < o ? key : o;
        u64 mx = key < o ? o : key;
        key = (low == up) ? mn : mx;
      }
    }
    if (l15 < 8)
      pk[((size_t)c * N_NODES + i) * 8 + l15] = key;
  }
}

// ---------------- merge 25 partial lists; flag rows needing exact fallback ----------------
__global__ __launch_bounds__(256) void k_topk_merge(
    const u64* __restrict__ pk, int* __restrict__ tk, int* __restrict__ flag) {
  int n = blockIdx.x * 256 + threadIdx.x;
  if (n >= N_NODES) return;
  u64 r[8];
  #pragma unroll
  for (int q = 0; q < 8; q++) r[q] = KEY_INF;
  for (int c = 0; c < NCHUNK; c++) {
    const u64* lst = pk + ((size_t)c * N_NODES + n) * 8;
    #pragma unroll
    for (int q = 0; q < 8; q++) {
      u64 key = lst[q];
      if (key >= r[7]) break;
      ins8(key, r);
    }
  }
  #pragma unroll
  for (int o = 0; o < 8; o++) tk[n * 8 + o] = (int)(r[o] & 0xFFF);
  float c8 = __uint_as_float((unsigned)(r[7] >> 12));
  flag[n] = (c8 > 6.28f) ? 1 : 0;
}

// ---------------- exact fp32 full-scan fallback for flagged rows ----------------
__global__ __launch_bounds__(256) void k_fb(
    const u16* __restrict__ fh, const u16* __restrict__ fl,
    const float* __restrict__ x2, const int* __restrict__ flag,
    int* __restrict__ tk) {
  int w = threadIdx.x >> 6, lane = threadIdx.x & 63;
  for (int rr = 0; rr < 16; rr++) {
    int n = blockIdx.x * 64 + w * 16 + rr;
    if (!flag[n]) continue;
    u64 top[8];
    #pragma unroll
    for (int q = 0; q < 8; q++) top[q] = KEY_INF;
    float x2i = x2[n];
    int iy = n >> 6, ix = n & 63;
    const u16* rh = fh + (size_t)n * C_DIM;
    const u16* rl = fl + (size_t)n * C_DIM;
    for (int jb = 0; jb < N_NODES; jb += 64) {
      int j = jb + lane;
      const u16* ch = fh + (size_t)j * C_DIM;
      const u16* cl = fl + (size_t)j * C_DIM;
      float dot = 0.0f;
      for (int k2 = 0; k2 < C_DIM; k2++)
        dot += (bf2f(rh[k2]) + bf2f(rl[k2])) * (bf2f(ch[k2]) + bf2f(cl[k2]));
      float d2 = x2i + x2[j] - 2.0f * dot;
      float fd = sqrtf(fmaxf(d2, 0.0f));
      float dy = (float)(iy - (j >> 6)), dx = (float)(ix - (j & 63));
      float sd = sqrtf(dy * dy + dx * dx);
      float comb = 0.7f * sd + 0.3f * fd;
      ins8(((u64)__float_as_uint(comb) << 12) | (u64)j, top);
    }
    #pragma unroll
    for (int d = 1; d < 64; d <<= 1) {
      u64 o[8];
      #pragma unroll
      for (int q = 0; q < 8; q++) o[q] = __shfl_xor(top[q], d);
      merge8(top, o);
    }
    if (lane == 0) {
      #pragma unroll
      for (int q = 0; q < 8; q++) tk[n * 8 + q] = (int)(top[q] & 0xFFF);
    }
  }
}

// ---------------- degree count ----------------
__global__ __launch_bounds__(256) void k_deg(const int* __restrict__ tk,
                                             int* __restrict__ deg) {
  int e = blockIdx.x * 256 + threadIdx.x;
  if (e < E_TOT) atomicAdd(&deg[tk[e]], 1);
}

// ---------------- exclusive scan (4096) + dinv ----------------
__global__ __launch_bounds__(256) void k_scan(const int* __restrict__ deg,
                                              int* __restrict__ offs,
                                              float* __restrict__ dinv) {
  __shared__ int ps[256];
  int t = threadIdx.x;
  int base = t * 16;
  int loc[16]; int s = 0;
  for (int i = 0; i < 16; i++) { int d = deg[base + i]; loc[i] = s; s += d; }
  ps[t] = s;
  __syncthreads();
  for (int d = 1; d < 256; d <<= 1) {
    int add = (t >= d) ? ps[t - d] : 0;
    __syncthreads();
    ps[t] += add;
    __syncthreads();
  }
  int cbase = (t == 0) ? 0 : ps[t - 1];
  for (int i = 0; i < 16; i++) offs[base + i] = cbase + loc[i];
  if (t == 255) offs[N_NODES] = ps[255];
  for (int i = 0; i < 16; i++)
    dinv[base + i] = 1.0f / sqrtf((float)deg[base + i]);
}

// ---------------- CSR fill ----------------
__global__ __launch_bounds__(256) void k_fill(const int* __restrict__ tk,
                                              const int* __restrict__ offs,
                                              int* __restrict__ cnt,
                                              int* __restrict__ insrc) {
  int e = blockIdx.x * 256 + threadIdx.x;
  if (e >= E_TOT) return;
  int i = e >> 3;
  int n = tk[e];
  int pos = offs[n] + atomicAdd(&cnt[n], 1);
  insrc[pos] = i;
}

// ---------------- per-node sort (determinism) ----------------
__global__ __launch_bounds__(256) void k_sort(const int* __restrict__ offs,
                                              int* __restrict__ insrc) {
  int n = blockIdx.x * 256 + threadIdx.x;
  if (n >= N_NODES) return;
  int beg = offs[n], end = offs[n + 1];
  for (int a = beg + 1; a < end; a++) {
    int v = insrc[a]; int p = a;
    while (p > beg && insrc[p - 1] > v) { insrc[p] = insrc[p - 1]; p--; }
    insrc[p] = v;
  }
}

// ---------------- bf16 MFMA GEMM, no LDS; wave = 64i x 64j ----------------
// EPI: 1 = bias+gelu -> bf16 out, 3 = plain -> bf16 out
__device__ __forceinline__ float gelu_f(float x) {
  const float k0 = 0.7978845608028654f;  // sqrt(2/pi)
  float x3 = x * x * x;
  return 0.5f * x * (1.0f + tanhf(k0 * (x + 0.044715f * x3)));
}

template <int EPI>
__global__ __launch_bounds__(256) void k_gemm_mfma(
    const u16* __restrict__ A, const u16* __restrict__ Bt,
    const float* __restrict__ bias, void* __restrict__ Cout,
    int M, int N, int K) {
  int t = threadIdx.x, lane = t & 63, w = t >> 6;
  int m0 = blockIdx.x * 256 + w * 64;
  int n0 = blockIdx.y * 64;
  int l15 = lane & 15;
  int kb = (lane >> 4) * 8;

  f32x4 acc[4][4];
  #pragma unroll
  for (int s = 0; s < 4; s++)
    #pragma unroll
    for (int nt = 0; nt < 4; nt++) acc[s][nt] = (f32x4){0.f, 0.f, 0.f, 0.f};

  const u16* ap = A + (size_t)(m0 + l15) * K + kb;
  const u16* bp[4];
  #pragma unroll
  for (int nt = 0; nt < 4; nt++) {
    int nr = n0 + nt * 16 + l15;
    bp[nt] = Bt + (size_t)(nr < N ? nr : 0) * K + kb;
  }
  const size_t RA = (size_t)16 * K;

  for (int kk = 0; kk < K; kk += 32) {
    bf16x8 a[4], b[4];
    #pragma unroll
    for (int s = 0; s < 4; s++) a[s] = *(const bf16x8*)(ap + s * RA + kk);
    #pragma unroll
    for (int nt = 0; nt < 4; nt++) b[nt] = *(const bf16x8*)(bp[nt] + kk);
    #pragma unroll
    for (int s = 0; s < 4; s++)
      #pragma unroll
      for (int nt = 0; nt < 4; nt++)
        acc[s][nt] = mfma16(a[s], b[nt], acc[s][nt]);
  }

  #pragma unroll
  for (int s = 0; s < 4; s++) {
    int rbase = m0 + s * 16 + ((lane >> 4) << 2);
    #pragma unroll
    for (int nt = 0; nt < 4; nt++) {
      int n = n0 + nt * 16 + l15;
      if (n >= N) continue;
      float bb = (EPI == 1) ? bias[n] : 0.0f;
      #pragma unroll
      for (int r = 0; r < 4; r++) {
        int m = rbase + r;
        float v = acc[s][nt][r];
        if (EPI == 1) { v += bb; v = gelu_f(v); }
        ((u16*)Cout)[(size_t)m * N + n] = f2bf(v);
      }
    }
  }
}

// ---------------- fused MLP tail: h2 = gelu(h1@U2+ub2); unc = sigmoid(h2@U3+ub3) ----------------
// A = h1b [M,192] bf16, Bt = U2t [96,192] bf16. Wave = 64 rows x all 96 cols.
__global__ __launch_bounds__(256) void k_mlp2(
    const u16* __restrict__ A, const u16* __restrict__ Bt,
    const float* __restrict__ ub2, const float* __restrict__ U3,
    const float* __restrict__ ub3, float* __restrict__ unc) {
  const int K = 192;
  int t = threadIdx.x, lane = t & 63, w = t >> 6;
  int m0 = blockIdx.x * 256 + w * 64;
  int l15 = lane & 15;
  int kb = (lane >> 4) * 8;

  f32x4 acc[4][6];
  #pragma unroll
  for (int s = 0; s < 4; s++)
    #pragma unroll
    for (int nt = 0; nt < 6; nt++) acc[s][nt] = (f32x4){0.f, 0.f, 0.f, 0.f};

  const u16* ap = A + (size_t)(m0 + l15) * K + kb;
  const u16* bp[6];
  #pragma unroll
  for (int nt = 0; nt < 6; nt++)
    bp[nt] = Bt + (size_t)(nt * 16 + l15) * K + kb;
  const size_t RA = (size_t)16 * K;

  #pragma unroll
  for (int kk = 0; kk < K; kk += 32) {
    bf16x8 a[4], b[6];
    #pragma unroll
    for (int s = 0; s < 4; s++) a[s] = *(const bf16x8*)(ap + s * RA + kk);
    #pragma unroll
    for (int nt = 0; nt < 6; nt++) b[nt] = *(const bf16x8*)(bp[nt] + kk);
    #pragma unroll
    for (int s = 0; s < 4; s++)
      #pragma unroll
      for (int nt = 0; nt < 6; nt++)
        acc[s][nt] = mfma16(a[s], b[nt], acc[s][nt]);
  }

  float ub3v = ub3[0];
  float u3v[6], b2v[6];
  #pragma unroll
  for (int nt = 0; nt < 6; nt++) {
    int col = nt * 16 + l15;
    u3v[nt] = U3[col];
    b2v[nt] = ub2[col];
  }
  #pragma unroll
  for (int s = 0; s < 4; s++) {
    #pragma unroll
    for (int r = 0; r < 4; r++) {
      float part = 0.0f;
      #pragma unroll
      for (int nt = 0; nt < 6; nt++)
        part += gelu_f(acc[s][nt][r] + b2v[nt]) * u3v[nt];
      #pragma unroll
      for (int d = 1; d < 16; d <<= 1) part += __shfl_xor(part, d);
      if (l15 == 0) {
        int m = m0 + s * 16 + ((lane >> 4) << 2) + r;
        unc[m] = 1.0f / (1.0f + expf(-(part + ub3v)));
      }
    }
  }
}

// ---------------- GCN aggregation, batch-fused: one node per 96-lane group,
// all 8 batch planes gathered per edge (8x memory-level parallelism) ----------------
__global__ __launch_bounds__(384) void k_gcn_agg(
    const u16* __restrict__ xw, u16* __restrict__ Xb,
    const float* __restrict__ bias, const float* __restrict__ dinv,
    const int* __restrict__ offs, const int* __restrict__ insrc) {
  const size_t PLANE = (size_t)N_NODES * C_DIM;
  int t = threadIdx.x;
  int g = t / 96, l = t % 96;           // group g: one node; lane l: 4 channels
  int n = blockIdx.x * 4 + g;
  int beg = offs[n], end = offs[n + 1];
  int c = 4 * l;
  const u16* base = xw + c;

  f32x4 a0 = {0,0,0,0}, a1 = {0,0,0,0}, a2 = {0,0,0,0}, a3 = {0,0,0,0};
  f32x4 a4 = {0,0,0,0}, a5 = {0,0,0,0}, a6 = {0,0,0,0}, a7 = {0,0,0,0};

  for (int e = beg; e < end; e++) {
    int i = insrc[e];
    float dv = dinv[i];
    const u16* rp = base + (size_t)i * C_DIM;
    ushort4 v0 = *(const ushort4*)(rp);
    ushort4 v1 = *(const ushort4*)(rp + PLANE);
    ushort4 v2 = *(const ushort4*)(rp + 2 * PLANE);
    ushort4 v3 = *(const ushort4*)(rp + 3 * PLANE);
    ushort4 v4 = *(const ushort4*)(rp + 4 * PLANE);
    ushort4 v5 = *(const ushort4*)(rp + 5 * PLANE);
    ushort4 v6 = *(const ushort4*)(rp + 6 * PLANE);
    ushort4 v7 = *(const ushort4*)(rp + 7 * PLANE);
    a0.x += dv * bf2f(v0.x); a0.y += dv * bf2f(v0.y); a0.z += dv * bf2f(v0.z); a0.w += dv * bf2f(v0.w);
    a1.x += dv * bf2f(v1.x); a1.y += dv * bf2f(v1.y); a1.z += dv * bf2f(v1.z); a1.w += dv * bf2f(v1.w);
    a2.x += dv * bf2f(v2.x); a2.y += dv * bf2f(v2.y); a2.z += dv * bf2f(v2.z); a2.w += dv * bf2f(v2.w);
    a3.x += dv * bf2f(v3.x); a3.y += dv * bf2f(v3.y); a3.z += dv * bf2f(v3.z); a3.w += dv * bf2f(v3.w);
    a4.x += dv * bf2f(v4.x); a4.y += dv * bf2f(v4.y); a4.z += dv * bf2f(v4.z); a4.w += dv * bf2f(v4.w);
    a5.x += dv * bf2f(v5.x); a5.y += dv * bf2f(v5.y); a5.z += dv * bf2f(v5.z); a5.w += dv * bf2f(v5.w);
    a6.x += dv * bf2f(v6.x); a6.y += dv * bf2f(v6.y); a6.z += dv * bf2f(v6.z); a6.w += dv * bf2f(v6.w);
    a7.x += dv * bf2f(v7.x); a7.y += dv * bf2f(v7.y); a7.z += dv * bf2f(v7.z); a7.w += dv * bf2f(v7.w);
  }

  float dn = dinv[n];
  float4 b4 = *(const float4*)(bias + c);
  size_t ob = (size_t)n * C_DIM + c;
  f32x4 av[8] = {a0, a1, a2, a3, a4, a5, a6, a7};
  #pragma unroll
  for (int b = 0; b < 8; b++) {
    size_t o = ob + (size_t)b * PLANE;
    ushort4 xo = *(ushort4*)(Xb + o);
    ushort4 xn;
    xn.x = f2bf(bf2f(xo.x) + fmaxf(dn * av[b].x + b4.x, 0.f));
    xn.y = f2bf(bf2f(xo.y) + fmaxf(dn * av[b].y + b4.y, 0.f));
    xn.z = f2bf(bf2f(xo.z) + fmaxf(dn * av[b].z + b4.z, 0.f));
    xn.w = f2bf(bf2f(xo.w) + fmaxf(dn * av[b].w + b4.w, 0.f));
    *(ushort4*)(Xb + o) = xn;
  }
}

// ---------------- out = fea * (1 + unc), float4 ----------------
__global__ __launch_bounds__(256) void k_final(
    const float* __restrict__ fea, const float* __restrict__ unc,
    float* __restrict__ out) {
  size_t i4 = (size_t)blockIdx.x * 256 + threadIdx.x;
  size_t idx = i4 * 4;
  if (idx >= (size_t)B_DIM * C_DIM * N_NODES) return;
  int b = (int)(idx / ((size_t)C_DIM * N_NODES));
  int n = (int)(idx & (N_NODES - 1));
  float4 f = *(const float4*)(fea + idx);
  float4 u = *(const float4*)(unc + (size_t)b * N_NODES + n);
  float4 o;
  o.x = f.x * (1.0f + u.x);
  o.y = f.y * (1.0f + u.y);
  o.z = f.z * (1.0f + u.z);
  o.w = f.w * (1.0f + u.w);
  *(float4*)(out + idx) = o;
}

extern "C" void kernel_launch(void* const* d_in, const int* in_sizes, int n_in,
                              void* d_out, int out_size, void* d_ws, size_t ws_size,
                              hipStream_t stream) {
  const float* fea = (const float*)d_in[0];
  const float* W1  = (const float*)d_in[1];
  const float* b1  = (const float*)d_in[2];
  const float* W2  = (const float*)d_in[3];
  const float* b2  = (const float*)d_in[4];
  const float* W3  = (const float*)d_in[5];
  const float* b3  = (const float*)d_in[6];
  const float* U1  = (const float*)d_in[7];
  const float* ub1 = (const float*)d_in[8];
  const float* U2  = (const float*)d_in[9];
  const float* ub2 = (const float*)d_in[10];
  const float* U3  = (const float*)d_in[11];
  const float* ub3 = (const float*)d_in[12];
  float* out = (float*)d_out;

  char* ws = (char*)d_ws;
  u16*   Xb   = (u16*)  (ws + 0);                       // 25165824
  u16*   XWb  = (u16*)  (ws + 25165824);                // 25165824
  u64*   pk   = (u64*)  (ws + 25165824);                // 6553600 (aliases XWb, pre-GEMM)
  u16*   h1b  = (u16*)  (ws + 25165824);                // 12582912 (aliases XWb, post-GCN)
  u16*   fh   = (u16*)  (ws + 50331648);                // 3145728
  u16*   fl   = (u16*)  (ws + 53477376);                // 3145728
  float* x2   = (float*)(ws + 56623104);                // 16384
  int*   tk   = (int*)  (ws + 56639488);                // 131072
  int*   deg  = (int*)  (ws + 56770560);                // 16384
  float* dinv = (float*)(ws + 56786944);                // 16384
  int*   offs = (int*)  (ws + 56803328);                // 16896
  int*   cnt  = (int*)  (ws + 56820224);                // 16384
  int*   insrc= (int*)  (ws + 56836608);                // 131072
  float* unc  = (float*)(ws + 56967680);                // 131072
  u16*   Wt1  = (u16*)  (ws + 57098752);                // 294912
  u16*   Wt2  = (u16*)  (ws + 57393664);                // 294912
  u16*   Wt3  = (u16*)  (ws + 57688576);                // 294912
  u16*   U1t  = (u16*)  (ws + 57983488);                // 147456
  u16*   U2t  = (u16*)  (ws + 58130944);                // 36864
  int*   flag = (int*)  (ws + 58167808);                // 16384

  // 0) weights -> transposed bf16
  k_prep_w<<<2088, 256, 0, stream>>>(W1, W2, W3, U1, U2, Wt1, Wt2, Wt3, U1t, U2t);
  // 1) transpose + mean -> Xb, fh/fl
  k_transpose_mean<<<dim3(N_NODES / 128, C_DIM / 32), dim3(32, 8), 0, stream>>>(
      fea, Xb, fh, fl);
  // 2) norms
  k_x2<<<N_NODES, 64, 0, stream>>>(fh, fl, x2);
  // 3) windowed distance top-8 (1 tile/wave), merge(+flag), fallback, degrees
  hipMemsetAsync(deg, 0, N_NODES * 4, stream);
  hipMemsetAsync(cnt, 0, N_NODES * 4, stream);
  k_dist_win<<<1600, 256, 0, stream>>>(fh, fl, x2, pk);
  k_topk_merge<<<N_NODES / 256, 256, 0, stream>>>(pk, tk, flag);
  k_fb<<<64, 256, 0, stream>>>(fh, fl, x2, flag, tk);
  k_deg<<<E_TOT / 256, 256, 0, stream>>>(tk, deg);
  // 4) graph build
  k_scan<<<1, 256, 0, stream>>>(deg, offs, dinv);
  k_fill<<<E_TOT / 256, 256, 0, stream>>>(tk, offs, cnt, insrc);
  k_sort<<<N_NODES / 256, 256, 0, stream>>>(offs, insrc);
  // 5) three GCN layers (bf16 MFMA GEMM + batch-fused aggregation)
  const u16* Wl[3] = {Wt1, Wt2, Wt3};
  const float* bl[3] = {b1, b2, b3};
  for (int l = 0; l < 3; l++) {
    k_gemm_mfma<3><<<dim3(M_ROWS / 256, C_DIM / 64), 256, 0, stream>>>(
        Xb, Wl[l], nullptr, XWb, M_ROWS, C_DIM, C_DIM);
    k_gcn_agg<<<N_NODES / 4, 384, 0, stream>>>(XWb, Xb, bl[l], dinv, offs, insrc);
  }
  // 6) MLP: h1 = gelu(Xb@U1+ub1) -> bf16; fused tail -> unc
  k_gemm_mfma<1><<<dim3(M_ROWS / 256, 3), 256, 0, stream>>>(
      Xb, U1t, ub1, h1b, M_ROWS, 192, C_DIM);
  k_mlp2<<<M_ROWS / 256, 256, 0, stream>>>(h1b, U2t, ub2, U3, ub3, unc);
  // 7) output
  size_t tot = (size_t)B_DIM * C_DIM * N_NODES;
  k_final<<<(tot / 4 + 255) / 256, 256, 0, stream>>>(fea, unc, out);
}

// Round 9
// 358.990 us; speedup vs baseline: 1.1131x; 1.1131x over previous
//
#include <hip/hip_runtime.h>
#include <hip/hip_bf16.h>
#include <math.h>

#define N_NODES 4096
#define C_DIM   384
#define B_DIM   8
#define K_NB    8
#define E_TOT   (N_NODES * K_NB)     // 32768
#define M_ROWS  (B_DIM * N_NODES)    // 32768
#define NCHUNK  4                    // one partial list per wave of the patch block
#define SROW    40                   // LDS row stride in u16 (32 data + 8 pad)

typedef unsigned long long u64;
typedef unsigned short u16;
typedef __attribute__((ext_vector_type(8))) short bf16x8;
typedef __attribute__((ext_vector_type(4))) float f32x4;
#define KEY_INF 0xFFFFFFFFFFFFFFFFull

__device__ __forceinline__ u16 f2bf(float f) {
  unsigned u = __float_as_uint(f);
  u += 0x7FFFu + ((u >> 16) & 1u);
  return (u16)(u >> 16);
}
__device__ __forceinline__ float bf2f(u16 h) {
  return __uint_as_float((unsigned)h << 16);
}
__device__ __forceinline__ f32x4 mfma16(bf16x8 a, bf16x8 b, f32x4 c) {
  return __builtin_amdgcn_mfma_f32_16x16x32_bf16(a, b, c, 0, 0, 0);
}

__device__ __forceinline__ void ce(u64& a, u64& b) {
  u64 lo = a < b ? a : b;
  u64 hi = a < b ? b : a;
  a = lo; b = hi;
}
__device__ __forceinline__ void ins8(u64 key, u64 (&r)[8]) {
  if (key < r[7]) {
    #pragma unroll
    for (int i = 0; i < 8; i++) {
      u64 lo = key < r[i] ? key : r[i];
      u64 hi = key < r[i] ? r[i] : key;
      r[i] = lo; key = hi;
    }
  }
}
// merge two ascending sorted-8 lists -> ascending 8 smallest
__device__ __forceinline__ void merge8(u64 (&r)[8], const u64 (&o)[8]) {
  u64 c[8];
  #pragma unroll
  for (int i = 0; i < 8; i++) c[i] = r[i] < o[7 - i] ? r[i] : o[7 - i];
  ce(c[0], c[4]); ce(c[1], c[5]); ce(c[2], c[6]); ce(c[3], c[7]);
  ce(c[0], c[2]); ce(c[1], c[3]); ce(c[4], c[6]); ce(c[5], c[7]);
  ce(c[0], c[1]); ce(c[2], c[3]); ce(c[4], c[5]); ce(c[6], c[7]);
  #pragma unroll
  for (int i = 0; i < 8; i++) r[i] = c[i];
}

// ---------------- weight prep: transpose + bf16 ----------------
__global__ __launch_bounds__(256) void k_prep_w(
    const float* __restrict__ W1, const float* __restrict__ W2,
    const float* __restrict__ W3, const float* __restrict__ U1,
    const float* __restrict__ U2,
    u16* __restrict__ Wt1, u16* __restrict__ Wt2, u16* __restrict__ Wt3,
    u16* __restrict__ U1t, u16* __restrict__ U2t) {
  int idx = blockIdx.x * 256 + threadIdx.x;
  if (idx < 147456) {
    int n = idx / 384, k = idx % 384;
    Wt1[idx] = f2bf(W1[k * 384 + n]);
  } else if (idx < 294912) {
    int i = idx - 147456; int n = i / 384, k = i % 384;
    Wt2[i] = f2bf(W2[k * 384 + n]);
  } else if (idx < 442368) {
    int i = idx - 294912; int n = i / 384, k = i % 384;
    Wt3[i] = f2bf(W3[k * 384 + n]);
  } else if (idx < 516096) {
    int i = idx - 442368; int n = i / 384, k = i % 384;
    U1t[i] = f2bf(U1[k * 192 + n]);
  } else if (idx < 534528) {
    int i = idx - 516096; int n = i / 192, k = i % 192;
    U2t[i] = f2bf(U2[k * 96 + n]);
  }
}

// ---------------- transpose + batch mean -> Xb (bf16) + fh/fl ----------------
__global__ __launch_bounds__(256) void k_transpose_mean(
    const float* __restrict__ fea, u16* __restrict__ Xb,
    u16* __restrict__ fh, u16* __restrict__ fl) {
  __shared__ float tb[32][132];
  __shared__ float ac[32][132];
  int n0 = blockIdx.x * 128, c0 = blockIdx.y * 32;
  int tx = threadIdx.x, ty = threadIdx.y;   // (32,8)
  for (int i = ty; i < 32; i += 8) {
    #pragma unroll
    for (int e = 0; e < 4; e++) ac[i][tx * 4 + e] = 0.0f;
  }
  __syncthreads();
  for (int b = 0; b < B_DIM; b++) {
    for (int i = ty; i < 32; i += 8) {
      float4 v = *(const float4*)(fea +
          ((size_t)b * C_DIM + (c0 + i)) * N_NODES + n0 + tx * 4);
      *(float4*)&tb[i][tx * 4] = v;
      ac[i][tx * 4 + 0] += v.x;
      ac[i][tx * 4 + 1] += v.y;
      ac[i][tx * 4 + 2] += v.z;
      ac[i][tx * 4 + 3] += v.w;
    }
    __syncthreads();
    for (int rr = ty; rr < 128; rr += 8) {
      size_t o = ((size_t)b * N_NODES + (n0 + rr)) * C_DIM + c0 + tx;
      Xb[o] = f2bf(tb[tx][rr]);
    }
    __syncthreads();
  }
  for (int rr = ty; rr < 128; rr += 8) {
    float m = ac[tx][rr] * 0.125f;
    u16 h = f2bf(m);
    size_t o = (size_t)(n0 + rr) * C_DIM + c0 + tx;
    fh[o] = h;
    fl[o] = f2bf(m - bf2f(h));
  }
}

// ---------------- squared norms (from hi+lo) ----------------
__global__ __launch_bounds__(64) void k_x2(const u16* __restrict__ fh,
                                           const u16* __restrict__ fl,
                                           float* __restrict__ x2) {
  int n = blockIdx.x;
  int lane = threadIdx.x;
  const u16* rh = fh + (size_t)n * C_DIM;
  const u16* rl = fl + (size_t)n * C_DIM;
  float s = 0.0f;
  for (int c = lane; c < C_DIM; c += 64) {
    float v = bf2f(rh[c]) + bf2f(rl[c]);
    s += v * v;
  }
  for (int d = 32; d > 0; d >>= 1) s += __shfl_down(s, d);
  if (lane == 0) x2[n] = s;
}

// ---------------- windowed distance + top-8, LDS-staged per-patch block ----------------
// One block per 4x4 patch. The 20x20 window (400 slots) x k-chunk(32) of fh/fl
// is staged into LDS with coalesced 16B loads (12 chunks over K=384), then the
// 4 waves compute 7/6/6/6 16-slot tiles via MFMA from LDS. Epilogue: per-lane
// ins8 over own candidates + 16-lane butterfly merge -> 4 partial lists/node.
// Also zeroes deg/cnt (blocks 0..15) for the later graph-build stages.
__global__ __launch_bounds__(256) void k_dist_win(
    const u16* __restrict__ fh, const u16* __restrict__ fl,
    const float* __restrict__ x2, u64* __restrict__ pk,
    int* __restrict__ deg, int* __restrict__ cnt) {
  __shared__ u16 WH[400 * SROW];
  __shared__ u16 WL[400 * SROW];
  int t = threadIdx.x;
  int lane = t & 63, w = t >> 6;
  int p = blockIdx.x;
  int py = p >> 4, px = p & 15;
  int iy0 = py * 4, ix0 = px * 4;
  int l15 = lane & 15;
  int kb = (lane >> 4) * 8;

  if (p < 16) { deg[p * 256 + t] = 0; cnt[p * 256 + t] = 0; }

  // wave's tiles: 7,6,6,6
  int t0 = (w == 0) ? 0 : 7 + (w - 1) * 6;
  int nt = w ? 6 : 7;

  // per-lane tile geometry
  int jj[7]; float x2j[7]; int jy_[7], jx_[7];
  #pragma unroll
  for (int tt = 0; tt < 7; tt++) {
    int s = (t0 + tt) * 16 + l15;
    int sy = s / 20, sx = s - sy * 20;
    int jy = iy0 - 8 + sy, jx = ix0 - 8 + sx;
    bool v = (tt < nt) && ((unsigned)jy < 64u) && ((unsigned)jx < 64u);
    jj[tt] = v ? (jy * 64 + jx) : -1;
    jy_[tt] = jy; jx_[tt] = jx;
    x2j[tt] = v ? x2[jy * 64 + jx] : 0.0f;
  }
  // A row (patch node l15) as a window slot
  int pr = 168 + (l15 >> 2) * 20 + (l15 & 3);

  // staging map: seg = t&3 (16B), rows r = (t>>2) + 64*it
  int seg = t & 3;
  int rb = t >> 2;

  f32x4 acc[7];
  #pragma unroll
  for (int tt = 0; tt < 7; tt++) acc[tt] = (f32x4){0.f, 0.f, 0.f, 0.f};

  for (int kc = 0; kc < 12; kc++) {
    int k0 = kc * 32;
    __syncthreads();
    #pragma unroll
    for (int it = 0; it < 7; it++) {
      int r = rb + 64 * it;
      if (r < 400) {
        int sy = r / 20, sx = r - sy * 20;
        int jy = iy0 - 8 + sy, jx = ix0 - 8 + sx;
        int j = (((unsigned)jy < 64u) && ((unsigned)jx < 64u)) ? jy * 64 + jx : 0;
        size_t src = (size_t)j * C_DIM + k0 + seg * 8;
        *(bf16x8*)&WH[r * SROW + seg * 8] = *(const bf16x8*)(fh + src);
        *(bf16x8*)&WL[r * SROW + seg * 8] = *(const bf16x8*)(fl + src);
      }
    }
    __syncthreads();
    bf16x8 aH = *(const bf16x8*)&WH[pr * SROW + kb];
    bf16x8 aL = *(const bf16x8*)&WL[pr * SROW + kb];
    #pragma unroll
    for (int tt = 0; tt < 7; tt++) {
      int row = (t0 + tt) * 16 + l15;
      bf16x8 bH = *(const bf16x8*)&WH[row * SROW + kb];
      bf16x8 bL = *(const bf16x8*)&WL[row * SROW + kb];
      acc[tt] = mfma16(aH, bH, acc[tt]);
      acc[tt] = mfma16(aL, bH, acc[tt]);
      acc[tt] = mfma16(aH, bL, acc[tt]);
    }
  }

  // epilogue: per output row, per-lane top-8 then 16-lane butterfly merge
  #pragma unroll
  for (int r = 0; r < 4; r++) {
    int r16 = ((lane >> 4) << 2) + r;
    int iy = iy0 + (r16 >> 2), ix = ix0 + (r16 & 3);
    int i = iy * 64 + ix;
    float x2i = x2[i];
    u64 top[8];
    #pragma unroll
    for (int q = 0; q < 8; q++) top[q] = KEY_INF;
    #pragma unroll
    for (int tt = 0; tt < 7; tt++) {
      float d2 = x2i + x2j[tt] - 2.0f * acc[tt][r];
      float fd = sqrtf(fmaxf(d2, 0.0f));
      float dy = (float)(iy - jy_[tt]), dx = (float)(ix - jx_[tt]);
      float sd = sqrtf(dy * dy + dx * dx);
      float comb = 0.7f * sd + 0.3f * fd;
      u64 key = (jj[tt] >= 0)
                    ? (((u64)__float_as_uint(comb) << 12) | (u64)jj[tt])
                    : KEY_INF;
      ins8(key, top);
    }
    #pragma unroll
    for (int d = 1; d < 16; d <<= 1) {
      u64 o[8];
      #pragma unroll
      for (int q = 0; q < 8; q++) o[q] = __shfl_xor(top[q], d);
      merge8(top, o);
    }
    if (l15 == 0) {
      #pragma unroll
      for (int q = 0; q < 8; q++)
        pk[((size_t)w * N_NODES + i) * 8 + q] = top[q];
    }
  }
}

// ---------------- merge 4 partial lists; count degrees; flag fallback rows ----------------
__global__ __launch_bounds__(256) void k_topk_merge(
    const u64* __restrict__ pk, int* __restrict__ tk, int* __restrict__ flag,
    int* __restrict__ deg) {
  int n = blockIdx.x * 256 + threadIdx.x;
  if (n >= N_NODES) return;
  u64 r[8];
  #pragma unroll
  for (int q = 0; q < 8; q++) r[q] = KEY_INF;
  for (int c = 0; c < NCHUNK; c++) {
    const u64* lst = pk + ((size_t)c * N_NODES + n) * 8;
    #pragma unroll
    for (int q = 0; q < 8; q++) {
      u64 key = lst[q];
      if (key >= r[7]) break;
      ins8(key, r);
    }
  }
  float c8 = __uint_as_float((unsigned)(r[7] >> 12));
  int fl = (c8 > 6.28f) ? 1 : 0;
  flag[n] = fl;
  #pragma unroll
  for (int o = 0; o < 8; o++) {
    int idx = (int)(r[o] & 0xFFF);
    tk[n * 8 + o] = idx;
    if (!fl) atomicAdd(&deg[idx], 1);
  }
}

// ---------------- exact fp32 full-scan fallback for flagged rows (+deg) ----------------
__global__ __launch_bounds__(256) void k_fb(
    const u16* __restrict__ fh, const u16* __restrict__ fl,
    const float* __restrict__ x2, const int* __restrict__ flag,
    int* __restrict__ tk, int* __restrict__ deg) {
  int w = threadIdx.x >> 6, lane = threadIdx.x & 63;
  for (int rr = 0; rr < 16; rr++) {
    int n = blockIdx.x * 64 + w * 16 + rr;
    if (!flag[n]) continue;
    u64 top[8];
    #pragma unroll
    for (int q = 0; q < 8; q++) top[q] = KEY_INF;
    float x2i = x2[n];
    int iy = n >> 6, ix = n & 63;
    const u16* rh = fh + (size_t)n * C_DIM;
    const u16* rl = fl + (size_t)n * C_DIM;
    for (int jb = 0; jb < N_NODES; jb += 64) {
      int j = jb + lane;
      const u16* ch = fh + (size_t)j * C_DIM;
      const u16* cl = fl + (size_t)j * C_DIM;
      float dot = 0.0f;
      for (int k2 = 0; k2 < C_DIM; k2++)
        dot += (bf2f(rh[k2]) + bf2f(rl[k2])) * (bf2f(ch[k2]) + bf2f(cl[k2]));
      float d2 = x2i + x2[j] - 2.0f * dot;
      float fd = sqrtf(fmaxf(d2, 0.0f));
      float dy = (float)(iy - (j >> 6)), dx = (float)(ix - (j & 63));
      float sd = sqrtf(dy * dy + dx * dx);
      float comb = 0.7f * sd + 0.3f * fd;
      ins8(((u64)__float_as_uint(comb) << 12) | (u64)j, top);
    }
    #pragma unroll
    for (int d = 1; d < 64; d <<= 1) {
      u64 o[8];
      #pragma unroll
      for (int q = 0; q < 8; q++) o[q] = __shfl_xor(top[q], d);
      merge8(top, o);
    }
    if (lane == 0) {
      #pragma unroll
      for (int q = 0; q < 8; q++) {
        int idx = (int)(top[q] & 0xFFF);
        tk[n * 8 + q] = idx;
        atomicAdd(&deg[idx], 1);
      }
    }
  }
}

// ---------------- exclusive scan (4096) + dinv ----------------
__global__ __launch_bounds__(256) void k_scan(const int* __restrict__ deg,
                                              int* __restrict__ offs,
                                              float* __restrict__ dinv) {
  __shared__ int ps[256];
  int t = threadIdx.x;
  int base = t * 16;
  int loc[16]; int s = 0;
  for (int i = 0; i < 16; i++) { int d = deg[base + i]; loc[i] = s; s += d; }
  ps[t] = s;
  __syncthreads();
  for (int d = 1; d < 256; d <<= 1) {
    int add = (t >= d) ? ps[t - d] : 0;
    __syncthreads();
    ps[t] += add;
    __syncthreads();
  }
  int cbase = (t == 0) ? 0 : ps[t - 1];
  for (int i = 0; i < 16; i++) offs[base + i] = cbase + loc[i];
  if (t == 255) offs[N_NODES] = ps[255];
  for (int i = 0; i < 16; i++)
    dinv[base + i] = 1.0f / sqrtf((float)deg[base + i]);
}

// ---------------- CSR fill ----------------
__global__ __launch_bounds__(256) void k_fill(const int* __restrict__ tk,
                                              const int* __restrict__ offs,
                                              int* __restrict__ cnt,
                                              int* __restrict__ insrc) {
  int e = blockIdx.x * 256 + threadIdx.x;
  if (e >= E_TOT) return;
  int i = e >> 3;
  int n = tk[e];
  int pos = offs[n] + atomicAdd(&cnt[n], 1);
  insrc[pos] = i;
}

// ---------------- per-node sort (determinism) ----------------
__global__ __launch_bounds__(256) void k_sort(const int* __restrict__ offs,
                                              int* __restrict__ insrc) {
  int n = blockIdx.x * 256 + threadIdx.x;
  if (n >= N_NODES) return;
  int beg = offs[n], end = offs[n + 1];
  for (int a = beg + 1; a < end; a++) {
    int v = insrc[a]; int p = a;
    while (p > beg && insrc[p - 1] > v) { insrc[p] = insrc[p - 1]; p--; }
    insrc[p] = v;
  }
}

// ---------------- bf16 MFMA GEMM, no LDS; wave = 64i x 64j ----------------
// EPI: 1 = bias+gelu -> bf16 out, 3 = plain -> bf16 out
__device__ __forceinline__ float gelu_f(float x) {
  const float k0 = 0.7978845608028654f;  // sqrt(2/pi)
  float x3 = x * x * x;
  return 0.5f * x * (1.0f + tanhf(k0 * (x + 0.044715f * x3)));
}

template <int EPI>
__global__ __launch_bounds__(256) void k_gemm_mfma(
    const u16* __restrict__ A, const u16* __restrict__ Bt,
    const float* __restrict__ bias, void* __restrict__ Cout,
    int M, int N, int K) {
  int t = threadIdx.x, lane = t & 63, w = t >> 6;
  int m0 = blockIdx.x * 256 + w * 64;
  int n0 = blockIdx.y * 64;
  int l15 = lane & 15;
  int kb = (lane >> 4) * 8;

  f32x4 acc[4][4];
  #pragma unroll
  for (int s = 0; s < 4; s++)
    #pragma unroll
    for (int nt = 0; nt < 4; nt++) acc[s][nt] = (f32x4){0.f, 0.f, 0.f, 0.f};

  const u16* ap = A + (size_t)(m0 + l15) * K + kb;
  const u16* bp[4];
  #pragma unroll
  for (int nt = 0; nt < 4; nt++) {
    int nr = n0 + nt * 16 + l15;
    bp[nt] = Bt + (size_t)(nr < N ? nr : 0) * K + kb;
  }
  const size_t RA = (size_t)16 * K;

  for (int kk = 0; kk < K; kk += 32) {
    bf16x8 a[4], b[4];
    #pragma unroll
    for (int s = 0; s < 4; s++) a[s] = *(const bf16x8*)(ap + s * RA + kk);
    #pragma unroll
    for (int nt = 0; nt < 4; nt++) b[nt] = *(const bf16x8*)(bp[nt] + kk);
    #pragma unroll
    for (int s = 0; s < 4; s++)
      #pragma unroll
      for (int nt = 0; nt < 4; nt++)
        acc[s][nt] = mfma16(a[s], b[nt], acc[s][nt]);
  }

  #pragma unroll
  for (int s = 0; s < 4; s++) {
    int rbase = m0 + s * 16 + ((lane >> 4) << 2);
    #pragma unroll
    for (int nt = 0; nt < 4; nt++) {
      int n = n0 + nt * 16 + l15;
      if (n >= N) continue;
      float bb = (EPI == 1) ? bias[n] : 0.0f;
      #pragma unroll
      for (int r = 0; r < 4; r++) {
        int m = rbase + r;
        float v = acc[s][nt][r];
        if (EPI == 1) { v += bb; v = gelu_f(v); }
        ((u16*)Cout)[(size_t)m * N + n] = f2bf(v);
      }
    }
  }
}

// ---------------- fused MLP tail: unc = sigmoid(gelu(h1@U2+ub2)@U3+ub3) ----------------
// A = h1b [M,192] bf16, Bt = U2t [96,192] bf16. Wave = 32 rows x all 96 cols.
__global__ __launch_bounds__(256) void k_mlp2(
    const u16* __restrict__ A, const u16* __restrict__ Bt,
    const float* __restrict__ ub2, const float* __restrict__ U3,
    const float* __restrict__ ub3, float* __restrict__ unc) {
  const int K = 192;
  int t = threadIdx.x, lane = t & 63, w = t >> 6;
  int m0 = blockIdx.x * 128 + w * 32;
  int l15 = lane & 15;
  int kb = (lane >> 4) * 8;

  f32x4 acc[2][6];
  #pragma unroll
  for (int s = 0; s < 2; s++)
    #pragma unroll
    for (int nt = 0; nt < 6; nt++) acc[s][nt] = (f32x4){0.f, 0.f, 0.f, 0.f};

  const u16* ap = A + (size_t)(m0 + l15) * K + kb;
  const u16* bp[6];
  #pragma unroll
  for (int nt = 0; nt < 6; nt++)
    bp[nt] = Bt + (size_t)(nt * 16 + l15) * K + kb;
  const size_t RA = (size_t)16 * K;

  #pragma unroll
  for (int kk = 0; kk < K; kk += 32) {
    bf16x8 a[2], b[6];
    #pragma unroll
    for (int s = 0; s < 2; s++) a[s] = *(const bf16x8*)(ap + s * RA + kk);
    #pragma unroll
    for (int nt = 0; nt < 6; nt++) b[nt] = *(const bf16x8*)(bp[nt] + kk);
    #pragma unroll
    for (int s = 0; s < 2; s++)
      #pragma unroll
      for (int nt = 0; nt < 6; nt++)
        acc[s][nt] = mfma16(a[s], b[nt], acc[s][nt]);
  }

  float ub3v = ub3[0];
  float u3v[6], b2v[6];
  #pragma unroll
  for (int nt = 0; nt < 6; nt++) {
    int col = nt * 16 + l15;
    u3v[nt] = U3[col];
    b2v[nt] = ub2[col];
  }
  #pragma unroll
  for (int s = 0; s < 2; s++) {
    #pragma unroll
    for (int r = 0; r < 4; r++) {
      float part = 0.0f;
      #pragma unroll
      for (int nt = 0; nt < 6; nt++)
        part += gelu_f(acc[s][nt][r] + b2v[nt]) * u3v[nt];
      #pragma unroll
      for (int d = 1; d < 16; d <<= 1) part += __shfl_xor(part, d);
      if (l15 == 0) {
        int m = m0 + s * 16 + ((lane >> 4) << 2) + r;
        unc[m] = 1.0f / (1.0f + expf(-(part + ub3v)));
      }
    }
  }
}

// ---------------- GCN aggregation, batch-fused ----------------
__global__ __launch_bounds__(384) void k_gcn_agg(
    const u16* __restrict__ xw, u16* __restrict__ Xb,
    const float* __restrict__ bias, const float* __restrict__ dinv,
    const int* __restrict__ offs, const int* __restrict__ insrc) {
  const size_t PLANE = (size_t)N_NODES * C_DIM;
  int t = threadIdx.x;
  int g = t / 96, l = t % 96;
  int n = blockIdx.x * 4 + g;
  int beg = offs[n], end = offs[n + 1];
  int c = 4 * l;
  const u16* base = xw + c;

  f32x4 a0 = {0,0,0,0}, a1 = {0,0,0,0}, a2 = {0,0,0,0}, a3 = {0,0,0,0};
  f32x4 a4 = {0,0,0,0}, a5 = {0,0,0,0}, a6 = {0,0,0,0}, a7 = {0,0,0,0};

  for (int e = beg; e < end; e++) {
    int i = insrc[e];
    float dv = dinv[i];
    const u16* rp = base + (size_t)i * C_DIM;
    ushort4 v0 = *(const ushort4*)(rp);
    ushort4 v1 = *(const ushort4*)(rp + PLANE);
    ushort4 v2 = *(const ushort4*)(rp + 2 * PLANE);
    ushort4 v3 = *(const ushort4*)(rp + 3 * PLANE);
    ushort4 v4 = *(const ushort4*)(rp + 4 * PLANE);
    ushort4 v5 = *(const ushort4*)(rp + 5 * PLANE);
    ushort4 v6 = *(const ushort4*)(rp + 6 * PLANE);
    ushort4 v7 = *(const ushort4*)(rp + 7 * PLANE);
    a0.x += dv * bf2f(v0.x); a0.y += dv * bf2f(v0.y); a0.z += dv * bf2f(v0.z); a0.w += dv * bf2f(v0.w);
    a1.x += dv * bf2f(v1.x); a1.y += dv * bf2f(v1.y); a1.z += dv * bf2f(v1.z); a1.w += dv * bf2f(v1.w);
    a2.x += dv * bf2f(v2.x); a2.y += dv * bf2f(v2.y); a2.z += dv * bf2f(v2.z); a2.w += dv * bf2f(v2.w);
    a3.x += dv * bf2f(v3.x); a3.y += dv * bf2f(v3.y); a3.z += dv * bf2f(v3.z); a3.w += dv * bf2f(v3.w);
    a4.x += dv * bf2f(v4.x); a4.y += dv * bf2f(v4.y); a4.z += dv * bf2f(v4.z); a4.w += dv * bf2f(v4.w);
    a5.x += dv * bf2f(v5.x); a5.y += dv * bf2f(v5.y); a5.z += dv * bf2f(v5.z); a5.w += dv * bf2f(v5.w);
    a6.x += dv * bf2f(v6.x); a6.y += dv * bf2f(v6.y); a6.z += dv * bf2f(v6.z); a6.w += dv * bf2f(v6.w);
    a7.x += dv * bf2f(v7.x); a7.y += dv * bf2f(v7.y); a7.z += dv * bf2f(v7.z); a7.w += dv * bf2f(v7.w);
  }

  float dn = dinv[n];
  float4 b4 = *(const float4*)(bias + c);
  size_t ob = (size_t)n * C_DIM + c;
  f32x4 av[8] = {a0, a1, a2, a3, a4, a5, a6, a7};
  #pragma unroll
  for (int b = 0; b < 8; b++) {
    size_t o = ob + (size_t)b * PLANE;
    ushort4 xo = *(ushort4*)(Xb + o);
    ushort4 xn;
    xn.x = f2bf(bf2f(xo.x) + fmaxf(dn * av[b].x + b4.x, 0.f));
    xn.y = f2bf(bf2f(xo.y) + fmaxf(dn * av[b].y + b4.y, 0.f));
    xn.z = f2bf(bf2f(xo.z) + fmaxf(dn * av[b].z + b4.z, 0.f));
    xn.w = f2bf(bf2f(xo.w) + fmaxf(dn * av[b].w + b4.w, 0.f));
    *(ushort4*)(Xb + o) = xn;
  }
}

// ---------------- out = fea * (1 + unc), float4 ----------------
__global__ __launch_bounds__(256) void k_final(
    const float* __restrict__ fea, const float* __restrict__ unc,
    float* __restrict__ out) {
  size_t i4 = (size_t)blockIdx.x * 256 + threadIdx.x;
  size_t idx = i4 * 4;
  if (idx >= (size_t)B_DIM * C_DIM * N_NODES) return;
  int b = (int)(idx / ((size_t)C_DIM * N_NODES));
  int n = (int)(idx & (N_NODES - 1));
  float4 f = *(const float4*)(fea + idx);
  float4 u = *(const float4*)(unc + (size_t)b * N_NODES + n);
  float4 o;
  o.x = f.x * (1.0f + u.x);
  o.y = f.y * (1.0f + u.y);
  o.z = f.z * (1.0f + u.z);
  o.w = f.w * (1.0f + u.w);
  *(float4*)(out + idx) = o;
}

extern "C" void kernel_launch(void* const* d_in, const int* in_sizes, int n_in,
                              void* d_out, int out_size, void* d_ws, size_t ws_size,
                              hipStream_t stream) {
  const float* fea = (const float*)d_in[0];
  const float* W1  = (const float*)d_in[1];
  const float* b1  = (const float*)d_in[2];
  const float* W2  = (const float*)d_in[3];
  const float* b2  = (const float*)d_in[4];
  const float* W3  = (const float*)d_in[5];
  const float* b3  = (const float*)d_in[6];
  const float* U1  = (const float*)d_in[7];
  const float* ub1 = (const float*)d_in[8];
  const float* U2  = (const float*)d_in[9];
  const float* ub2 = (const float*)d_in[10];
  const float* U3  = (const float*)d_in[11];
  const float* ub3 = (const float*)d_in[12];
  float* out = (float*)d_out;

  char* ws = (char*)d_ws;
  u16*   Xb   = (u16*)  (ws + 0);                       // 25165824
  u16*   XWb  = (u16*)  (ws + 25165824);                // 25165824
  u64*   pk   = (u64*)  (ws + 25165824);                // 1048576 (aliases XWb, pre-GEMM)
  u16*   h1b  = (u16*)  (ws + 25165824);                // 12582912 (aliases XWb, post-GCN)
  u16*   fh   = (u16*)  (ws + 50331648);                // 3145728
  u16*   fl   = (u16*)  (ws + 53477376);                // 3145728
  float* x2   = (float*)(ws + 56623104);                // 16384
  int*   tk   = (int*)  (ws + 56639488);                // 131072
  int*   deg  = (int*)  (ws + 56770560);                // 16384
  float* dinv = (float*)(ws + 56786944);                // 16384
  int*   offs = (int*)  (ws + 56803328);                // 16896
  int*   cnt  = (int*)  (ws + 56820224);                // 16384
  int*   insrc= (int*)  (ws + 56836608);                // 131072
  float* unc  = (float*)(ws + 56967680);                // 131072
  u16*   Wt1  = (u16*)  (ws + 57098752);                // 294912
  u16*   Wt2  = (u16*)  (ws + 57393664);                // 294912
  u16*   Wt3  = (u16*)  (ws + 57688576);                // 294912
  u16*   U1t  = (u16*)  (ws + 57983488);                // 147456
  u16*   U2t  = (u16*)  (ws + 58130944);                // 36864
  int*   flag = (int*)  (ws + 58167808);                // 16384

  // 0) weights -> transposed bf16
  k_prep_w<<<2088, 256, 0, stream>>>(W1, W2, W3, U1, U2, Wt1, Wt2, Wt3, U1t, U2t);
  // 1) transpose + mean -> Xb, fh/fl
  k_transpose_mean<<<dim3(N_NODES / 128, C_DIM / 32), dim3(32, 8), 0, stream>>>(
      fea, Xb, fh, fl);
  // 2) norms
  k_x2<<<N_NODES, 64, 0, stream>>>(fh, fl, x2);
  // 3) windowed distance top-8 (LDS-staged, zeroes deg/cnt), merge(+deg/flag),
  //    exact fallback (+deg)
  k_dist_win<<<256, 256, 0, stream>>>(fh, fl, x2, pk, deg, cnt);
  k_topk_merge<<<N_NODES / 256, 256, 0, stream>>>(pk, tk, flag, deg);
  k_fb<<<64, 256, 0, stream>>>(fh, fl, x2, flag, tk, deg);
  // 4) graph build
  k_scan<<<1, 256, 0, stream>>>(deg, offs, dinv);
  k_fill<<<E_TOT / 256, 256, 0, stream>>>(tk, offs, cnt, insrc);
  k_sort<<<N_NODES / 256, 256, 0, stream>>>(offs, insrc);
  // 5) three GCN layers (bf16 MFMA GEMM + batch-fused aggregation)
  const u16* Wl[3] = {Wt1, Wt2, Wt3};
  const float* bl[3] = {b1, b2, b3};
  for (int l = 0; l < 3; l++) {
    k_gemm_mfma<3><<<dim3(M_ROWS / 256, C_DIM / 64), 256, 0, stream>>>(
        Xb, Wl[l], nullptr, XWb, M_ROWS, C_DIM, C_DIM);
    k_gcn_agg<<<N_NODES / 4, 384, 0, stream>>>(XWb, Xb, bl[l], dinv, offs, insrc);
  }
  // 6) MLP: h1 = gelu(Xb@U1+ub1) -> bf16; fused tail -> unc
  k_gemm_mfma<1><<<dim3(M_ROWS / 256, 3), 256, 0, stream>>>(
      Xb, U1t, ub1, h1b, M_ROWS, 192, C_DIM);
  k_mlp2<<<M_ROWS / 128, 256, 0, stream>>>(h1b, U2t, ub2, U3, ub3, unc);
  // 7) output
  size_t tot = (size_t)B_DIM * C_DIM * N_NODES;
  k_final<<<(tot / 4 + 255) / 256, 256, 0, stream>>>(fea, unc, out);
}

// Round 10
// 289.262 us; speedup vs baseline: 1.3814x; 1.2411x over previous
//
#include <hip/hip_runtime.h>
#include <hip/hip_bf16.h>
#include <math.h>

#define N_NODES 4096
#define C_DIM   384
#define B_DIM   8
#define K_NB    8
#define E_TOT   (N_NODES * K_NB)     // 32768
#define M_ROWS  (B_DIM * N_NODES)    // 32768
#define NCHUNK  4                    // one partial list per wave of the patch block
#define SROW    40                   // dist-win LDS row stride in u16 (32 data + 8 pad)
#define GSW     40                   // gemm LDS row stride in u16 (32 data + 8 pad, 16B-aligned)

typedef unsigned long long u64;
typedef unsigned short u16;
typedef __attribute__((ext_vector_type(8))) short bf16x8;
typedef __attribute__((ext_vector_type(4))) float f32x4;
#define KEY_INF 0xFFFFFFFFFFFFFFFFull

__device__ __forceinline__ u16 f2bf(float f) {
  unsigned u = __float_as_uint(f);
  u += 0x7FFFu + ((u >> 16) & 1u);
  return (u16)(u >> 16);
}
__device__ __forceinline__ float bf2f(u16 h) {
  return __uint_as_float((unsigned)h << 16);
}
__device__ __forceinline__ f32x4 mfma16(bf16x8 a, bf16x8 b, f32x4 c) {
  return __builtin_amdgcn_mfma_f32_16x16x32_bf16(a, b, c, 0, 0, 0);
}

__device__ __forceinline__ void ce(u64& a, u64& b) {
  u64 lo = a < b ? a : b;
  u64 hi = a < b ? b : a;
  a = lo; b = hi;
}
__device__ __forceinline__ void ins8(u64 key, u64 (&r)[8]) {
  if (key < r[7]) {
    #pragma unroll
    for (int i = 0; i < 8; i++) {
      u64 lo = key < r[i] ? key : r[i];
      u64 hi = key < r[i] ? r[i] : key;
      r[i] = lo; key = hi;
    }
  }
}
// merge two ascending sorted-8 lists -> ascending 8 smallest
__device__ __forceinline__ void merge8(u64 (&r)[8], const u64 (&o)[8]) {
  u64 c[8];
  #pragma unroll
  for (int i = 0; i < 8; i++) c[i] = r[i] < o[7 - i] ? r[i] : o[7 - i];
  ce(c[0], c[4]); ce(c[1], c[5]); ce(c[2], c[6]); ce(c[3], c[7]);
  ce(c[0], c[2]); ce(c[1], c[3]); ce(c[4], c[6]); ce(c[5], c[7]);
  ce(c[0], c[1]); ce(c[2], c[3]); ce(c[4], c[5]); ce(c[6], c[7]);
  #pragma unroll
  for (int i = 0; i < 8; i++) r[i] = c[i];
}

// ---------------- weight prep: transpose + bf16 ----------------
__global__ __launch_bounds__(256) void k_prep_w(
    const float* __restrict__ W1, const float* __restrict__ W2,
    const float* __restrict__ W3, const float* __restrict__ U1,
    const float* __restrict__ U2,
    u16* __restrict__ Wt1, u16* __restrict__ Wt2, u16* __restrict__ Wt3,
    u16* __restrict__ U1t, u16* __restrict__ U2t) {
  int idx = blockIdx.x * 256 + threadIdx.x;
  if (idx < 147456) {
    int n = idx / 384, k = idx % 384;
    Wt1[idx] = f2bf(W1[k * 384 + n]);
  } else if (idx < 294912) {
    int i = idx - 147456; int n = i / 384, k = i % 384;
    Wt2[i] = f2bf(W2[k * 384 + n]);
  } else if (idx < 442368) {
    int i = idx - 294912; int n = i / 384, k = i % 384;
    Wt3[i] = f2bf(W3[k * 384 + n]);
  } else if (idx < 516096) {
    int i = idx - 442368; int n = i / 384, k = i % 384;
    U1t[i] = f2bf(U1[k * 192 + n]);
  } else if (idx < 534528) {
    int i = idx - 516096; int n = i / 192, k = i % 192;
    U2t[i] = f2bf(U2[k * 96 + n]);
  }
}

// ---------------- transpose + batch mean -> Xb (bf16) + fh/fl ----------------
__global__ __launch_bounds__(256) void k_transpose_mean(
    const float* __restrict__ fea, u16* __restrict__ Xb,
    u16* __restrict__ fh, u16* __restrict__ fl) {
  __shared__ float tb[32][132];
  __shared__ float ac[32][132];
  int n0 = blockIdx.x * 128, c0 = blockIdx.y * 32;
  int tx = threadIdx.x, ty = threadIdx.y;   // (32,8)
  for (int i = ty; i < 32; i += 8) {
    #pragma unroll
    for (int e = 0; e < 4; e++) ac[i][tx * 4 + e] = 0.0f;
  }
  __syncthreads();
  for (int b = 0; b < B_DIM; b++) {
    for (int i = ty; i < 32; i += 8) {
      float4 v = *(const float4*)(fea +
          ((size_t)b * C_DIM + (c0 + i)) * N_NODES + n0 + tx * 4);
      *(float4*)&tb[i][tx * 4] = v;
      ac[i][tx * 4 + 0] += v.x;
      ac[i][tx * 4 + 1] += v.y;
      ac[i][tx * 4 + 2] += v.z;
      ac[i][tx * 4 + 3] += v.w;
    }
    __syncthreads();
    for (int rr = ty; rr < 128; rr += 8) {
      size_t o = ((size_t)b * N_NODES + (n0 + rr)) * C_DIM + c0 + tx;
      Xb[o] = f2bf(tb[tx][rr]);
    }
    __syncthreads();
  }
  for (int rr = ty; rr < 128; rr += 8) {
    float m = ac[tx][rr] * 0.125f;
    u16 h = f2bf(m);
    size_t o = (size_t)(n0 + rr) * C_DIM + c0 + tx;
    fh[o] = h;
    fl[o] = f2bf(m - bf2f(h));
  }
}

// ---------------- squared norms (from hi+lo) ----------------
__global__ __launch_bounds__(64) void k_x2(const u16* __restrict__ fh,
                                           const u16* __restrict__ fl,
                                           float* __restrict__ x2) {
  int n = blockIdx.x;
  int lane = threadIdx.x;
  const u16* rh = fh + (size_t)n * C_DIM;
  const u16* rl = fl + (size_t)n * C_DIM;
  float s = 0.0f;
  for (int c = lane; c < C_DIM; c += 64) {
    float v = bf2f(rh[c]) + bf2f(rl[c]);
    s += v * v;
  }
  for (int d = 32; d > 0; d >>= 1) s += __shfl_down(s, d);
  if (lane == 0) x2[n] = s;
}

// ---------------- windowed distance + top-8, LDS-staged per-patch block ----------------
__global__ __launch_bounds__(256) void k_dist_win(
    const u16* __restrict__ fh, const u16* __restrict__ fl,
    const float* __restrict__ x2, u64* __restrict__ pk,
    int* __restrict__ deg, int* __restrict__ cnt) {
  __shared__ u16 WH[400 * SROW];
  __shared__ u16 WL[400 * SROW];
  int t = threadIdx.x;
  int lane = t & 63, w = t >> 6;
  int p = blockIdx.x;
  int py = p >> 4, px = p & 15;
  int iy0 = py * 4, ix0 = px * 4;
  int l15 = lane & 15;
  int kb = (lane >> 4) * 8;

  if (p < 16) { deg[p * 256 + t] = 0; cnt[p * 256 + t] = 0; }

  int t0 = (w == 0) ? 0 : 7 + (w - 1) * 6;
  int nt = w ? 6 : 7;

  int jj[7]; float x2j[7]; int jy_[7], jx_[7];
  #pragma unroll
  for (int tt = 0; tt < 7; tt++) {
    int s = (t0 + tt) * 16 + l15;
    int sy = s / 20, sx = s - sy * 20;
    int jy = iy0 - 8 + sy, jx = ix0 - 8 + sx;
    bool v = (tt < nt) && ((unsigned)jy < 64u) && ((unsigned)jx < 64u);
    jj[tt] = v ? (jy * 64 + jx) : -1;
    jy_[tt] = jy; jx_[tt] = jx;
    x2j[tt] = v ? x2[jy * 64 + jx] : 0.0f;
  }
  int pr = 168 + (l15 >> 2) * 20 + (l15 & 3);

  int seg = t & 3;
  int rb = t >> 2;

  f32x4 acc[7];
  #pragma unroll
  for (int tt = 0; tt < 7; tt++) acc[tt] = (f32x4){0.f, 0.f, 0.f, 0.f};

  for (int kc = 0; kc < 12; kc++) {
    int k0 = kc * 32;
    __syncthreads();
    #pragma unroll
    for (int it = 0; it < 7; it++) {
      int r = rb + 64 * it;
      if (r < 400) {
        int sy = r / 20, sx = r - sy * 20;
        int jy = iy0 - 8 + sy, jx = ix0 - 8 + sx;
        int j = (((unsigned)jy < 64u) && ((unsigned)jx < 64u)) ? jy * 64 + jx : 0;
        size_t src = (size_t)j * C_DIM + k0 + seg * 8;
        *(bf16x8*)&WH[r * SROW + seg * 8] = *(const bf16x8*)(fh + src);
        *(bf16x8*)&WL[r * SROW + seg * 8] = *(const bf16x8*)(fl + src);
      }
    }
    __syncthreads();
    bf16x8 aH = *(const bf16x8*)&WH[pr * SROW + kb];
    bf16x8 aL = *(const bf16x8*)&WL[pr * SROW + kb];
    #pragma unroll
    for (int tt = 0; tt < 7; tt++) {
      int row = (t0 + tt) * 16 + l15;
      bf16x8 bH = *(const bf16x8*)&WH[row * SROW + kb];
      bf16x8 bL = *(const bf16x8*)&WL[row * SROW + kb];
      acc[tt] = mfma16(aH, bH, acc[tt]);
      acc[tt] = mfma16(aL, bH, acc[tt]);
      acc[tt] = mfma16(aH, bL, acc[tt]);
    }
  }

  #pragma unroll
  for (int r = 0; r < 4; r++) {
    int r16 = ((lane >> 4) << 2) + r;
    int iy = iy0 + (r16 >> 2), ix = ix0 + (r16 & 3);
    int i = iy * 64 + ix;
    float x2i = x2[i];
    u64 top[8];
    #pragma unroll
    for (int q = 0; q < 8; q++) top[q] = KEY_INF;
    #pragma unroll
    for (int tt = 0; tt < 7; tt++) {
      float d2 = x2i + x2j[tt] - 2.0f * acc[tt][r];
      float fd = sqrtf(fmaxf(d2, 0.0f));
      float dy = (float)(iy - jy_[tt]), dx = (float)(ix - jx_[tt]);
      float sd = sqrtf(dy * dy + dx * dx);
      float comb = 0.7f * sd + 0.3f * fd;
      u64 key = (jj[tt] >= 0)
                    ? (((u64)__float_as_uint(comb) << 12) | (u64)jj[tt])
                    : KEY_INF;
      ins8(key, top);
    }
    #pragma unroll
    for (int d = 1; d < 16; d <<= 1) {
      u64 o[8];
      #pragma unroll
      for (int q = 0; q < 8; q++) o[q] = __shfl_xor(top[q], d);
      merge8(top, o);
    }
    if (l15 == 0) {
      #pragma unroll
      for (int q = 0; q < 8; q++)
        pk[((size_t)w * N_NODES + i) * 8 + q] = top[q];
    }
  }
}

// ---------------- merge 4 partial lists; count degrees; flag fallback rows ----------------
__global__ __launch_bounds__(256) void k_topk_merge(
    const u64* __restrict__ pk, int* __restrict__ tk, int* __restrict__ flag,
    int* __restrict__ deg) {
  int n = blockIdx.x * 256 + threadIdx.x;
  if (n >= N_NODES) return;
  u64 r[8];
  #pragma unroll
  for (int q = 0; q < 8; q++) r[q] = KEY_INF;
  for (int c = 0; c < NCHUNK; c++) {
    const u64* lst = pk + ((size_t)c * N_NODES + n) * 8;
    #pragma unroll
    for (int q = 0; q < 8; q++) {
      u64 key = lst[q];
      if (key >= r[7]) break;
      ins8(key, r);
    }
  }
  float c8 = __uint_as_float((unsigned)(r[7] >> 12));
  int fl = (c8 > 6.28f) ? 1 : 0;
  flag[n] = fl;
  #pragma unroll
  for (int o = 0; o < 8; o++) {
    int idx = (int)(r[o] & 0xFFF);
    tk[n * 8 + o] = idx;
    if (!fl) atomicAdd(&deg[idx], 1);
  }
}

// ---------------- exact fp32 full-scan fallback for flagged rows (+deg) ----------------
__global__ __launch_bounds__(256) void k_fb(
    const u16* __restrict__ fh, const u16* __restrict__ fl,
    const float* __restrict__ x2, const int* __restrict__ flag,
    int* __restrict__ tk, int* __restrict__ deg) {
  int w = threadIdx.x >> 6, lane = threadIdx.x & 63;
  for (int rr = 0; rr < 16; rr++) {
    int n = blockIdx.x * 64 + w * 16 + rr;
    if (!flag[n]) continue;
    u64 top[8];
    #pragma unroll
    for (int q = 0; q < 8; q++) top[q] = KEY_INF;
    float x2i = x2[n];
    int iy = n >> 6, ix = n & 63;
    const u16* rh = fh + (size_t)n * C_DIM;
    const u16* rl = fl + (size_t)n * C_DIM;
    for (int jb = 0; jb < N_NODES; jb += 64) {
      int j = jb + lane;
      const u16* ch = fh + (size_t)j * C_DIM;
      const u16* cl = fl + (size_t)j * C_DIM;
      float dot = 0.0f;
      for (int k2 = 0; k2 < C_DIM; k2++)
        dot += (bf2f(rh[k2]) + bf2f(rl[k2])) * (bf2f(ch[k2]) + bf2f(cl[k2]));
      float d2 = x2i + x2[j] - 2.0f * dot;
      float fd = sqrtf(fmaxf(d2, 0.0f));
      float dy = (float)(iy - (j >> 6)), dx = (float)(ix - (j & 63));
      float sd = sqrtf(dy * dy + dx * dx);
      float comb = 0.7f * sd + 0.3f * fd;
      ins8(((u64)__float_as_uint(comb) << 12) | (u64)j, top);
    }
    #pragma unroll
    for (int d = 1; d < 64; d <<= 1) {
      u64 o[8];
      #pragma unroll
      for (int q = 0; q < 8; q++) o[q] = __shfl_xor(top[q], d);
      merge8(top, o);
    }
    if (lane == 0) {
      #pragma unroll
      for (int q = 0; q < 8; q++) {
        int idx = (int)(top[q] & 0xFFF);
        tk[n * 8 + q] = idx;
        atomicAdd(&deg[idx], 1);
      }
    }
  }
}

// ---------------- exclusive scan (4096) + dinv ----------------
__global__ __launch_bounds__(256) void k_scan(const int* __restrict__ deg,
                                              int* __restrict__ offs,
                                              float* __restrict__ dinv) {
  __shared__ int ps[256];
  int t = threadIdx.x;
  int base = t * 16;
  int loc[16]; int s = 0;
  for (int i = 0; i < 16; i++) { int d = deg[base + i]; loc[i] = s; s += d; }
  ps[t] = s;
  __syncthreads();
  for (int d = 1; d < 256; d <<= 1) {
    int add = (t >= d) ? ps[t - d] : 0;
    __syncthreads();
    ps[t] += add;
    __syncthreads();
  }
  int cbase = (t == 0) ? 0 : ps[t - 1];
  for (int i = 0; i < 16; i++) offs[base + i] = cbase + loc[i];
  if (t == 255) offs[N_NODES] = ps[255];
  for (int i = 0; i < 16; i++)
    dinv[base + i] = 1.0f / sqrtf((float)deg[base + i]);
}

// ---------------- CSR fill ----------------
__global__ __launch_bounds__(256) void k_fill(const int* __restrict__ tk,
                                              const int* __restrict__ offs,
                                              int* __restrict__ cnt,
                                              int* __restrict__ insrc) {
  int e = blockIdx.x * 256 + threadIdx.x;
  if (e >= E_TOT) return;
  int i = e >> 3;
  int n = tk[e];
  int pos = offs[n] + atomicAdd(&cnt[n], 1);
  insrc[pos] = i;
}

// ---------------- per-node sort (determinism) ----------------
__global__ __launch_bounds__(256) void k_sort(const int* __restrict__ offs,
                                              int* __restrict__ insrc) {
  int n = blockIdx.x * 256 + threadIdx.x;
  if (n >= N_NODES) return;
  int beg = offs[n], end = offs[n + 1];
  for (int a = beg + 1; a < end; a++) {
    int v = insrc[a]; int p = a;
    while (p > beg && insrc[p - 1] > v) { insrc[p] = insrc[p - 1]; p--; }
    insrc[p] = v;
  }
}

// ---------------- LDS-staged bf16 MFMA GEMM (2-phase, reg-staging) ----------------
// C[M,N] = A[M,K] @ Bt[N,K]^T, 128x128 tile, BK=32, 4 waves 2x2 (64x64 each).
// Per k-step: issue next-tile global loads (regs) -> ds_read+16 MFMA -> barrier
// -> ds_write next tile -> barrier. EPI: 1 = bias+gelu, 3 = plain. bf16 out.
__device__ __forceinline__ float gelu_f(float x) {
  const float k0 = 0.7978845608028654f;  // sqrt(2/pi)
  float x3 = x * x * x;
  return 0.5f * x * (1.0f + tanhf(k0 * (x + 0.044715f * x3)));
}

template <int EPI>
__global__ __launch_bounds__(256) void k_gemm_lds(
    const u16* __restrict__ A, const u16* __restrict__ Bt,
    const float* __restrict__ bias, u16* __restrict__ Cout,
    int M, int N, int K) {
  __shared__ u16 As[128 * GSW];
  __shared__ u16 Bs[128 * GSW];
  int t = threadIdx.x, lane = t & 63, w = t >> 6;
  int m0 = blockIdx.x * 128;
  int n0 = blockIdx.y * 128;
  int l15 = lane & 15;
  int kg = lane >> 4;           // k-segment 0..3 (8 elems each)
  int wr = (w >> 1) * 64;       // wave row offset
  int wc = (w & 1) * 64;        // wave col offset

  // staging: thread t owns tile row tr = t>>1, 32B half (t&1)
  int tr = t >> 1;
  int ks2 = (t & 1) * 16;       // element offset within the 32-elem k-chunk
  const u16* gA = A + (size_t)(m0 + tr) * K + ks2;
  int nrow = n0 + tr;
  const u16* gB = Bt + (size_t)(nrow < N ? nrow : 0) * K + ks2;
  int ldso = tr * GSW + ks2;

  f32x4 acc[4][4];
  #pragma unroll
  for (int s = 0; s < 4; s++)
    #pragma unroll
    for (int nt = 0; nt < 4; nt++) acc[s][nt] = (f32x4){0.f, 0.f, 0.f, 0.f};

  // prologue: stage tile 0
  bf16x8 ra0 = *(const bf16x8*)(gA);
  bf16x8 ra1 = *(const bf16x8*)(gA + 8);
  bf16x8 rb0 = *(const bf16x8*)(gB);
  bf16x8 rb1 = *(const bf16x8*)(gB + 8);
  *(bf16x8*)&As[ldso] = ra0;
  *(bf16x8*)&As[ldso + 8] = ra1;
  *(bf16x8*)&Bs[ldso] = rb0;
  *(bf16x8*)&Bs[ldso + 8] = rb1;
  __syncthreads();

  int NT = K / 32;
  for (int kt = 0; kt < NT; kt++) {
    // issue next-tile loads early (latency hides under MFMA below)
    if (kt + 1 < NT) {
      int ko = (kt + 1) * 32;
      ra0 = *(const bf16x8*)(gA + ko);
      ra1 = *(const bf16x8*)(gA + ko + 8);
      rb0 = *(const bf16x8*)(gB + ko);
      rb1 = *(const bf16x8*)(gB + ko + 8);
    }
    // compute current tile from LDS
    bf16x8 a[4], b[4];
    #pragma unroll
    for (int s = 0; s < 4; s++)
      a[s] = *(const bf16x8*)&As[(wr + s * 16 + l15) * GSW + kg * 8];
    #pragma unroll
    for (int nt = 0; nt < 4; nt++)
      b[nt] = *(const bf16x8*)&Bs[(wc + nt * 16 + l15) * GSW + kg * 8];
    #pragma unroll
    for (int s = 0; s < 4; s++)
      #pragma unroll
      for (int nt = 0; nt < 4; nt++)
        acc[s][nt] = mfma16(a[s], b[nt], acc[s][nt]);
    if (kt + 1 < NT) {
      __syncthreads();            // all ds_reads of tile kt done
      *(bf16x8*)&As[ldso] = ra0;
      *(bf16x8*)&As[ldso + 8] = ra1;
      *(bf16x8*)&Bs[ldso] = rb0;
      *(bf16x8*)&Bs[ldso + 8] = rb1;
      __syncthreads();            // tile kt+1 visible
    }
  }

  #pragma unroll
  for (int s = 0; s < 4; s++) {
    int rbase = m0 + wr + s * 16 + ((lane >> 4) << 2);
    #pragma unroll
    for (int nt = 0; nt < 4; nt++) {
      int n = n0 + wc + nt * 16 + l15;
      if (n >= N) continue;
      float bb = (EPI == 1) ? bias[n] : 0.0f;
      #pragma unroll
      for (int r = 0; r < 4; r++) {
        int m = rbase + r;
        float v = acc[s][nt][r];
        if (EPI == 1) { v += bb; v = gelu_f(v); }
        Cout[(size_t)m * N + n] = f2bf(v);
      }
    }
  }
}

// ---------------- fused MLP tail: unc = sigmoid(gelu(h1@U2+ub2)@U3+ub3) ----------------
__global__ __launch_bounds__(256) void k_mlp2(
    const u16* __restrict__ A, const u16* __restrict__ Bt,
    const float* __restrict__ ub2, const float* __restrict__ U3,
    const float* __restrict__ ub3, float* __restrict__ unc) {
  const int K = 192;
  int t = threadIdx.x, lane = t & 63, w = t >> 6;
  int m0 = blockIdx.x * 128 + w * 32;
  int l15 = lane & 15;
  int kb = (lane >> 4) * 8;

  f32x4 acc[2][6];
  #pragma unroll
  for (int s = 0; s < 2; s++)
    #pragma unroll
    for (int nt = 0; nt < 6; nt++) acc[s][nt] = (f32x4){0.f, 0.f, 0.f, 0.f};

  const u16* ap = A + (size_t)(m0 + l15) * K + kb;
  const u16* bp[6];
  #pragma unroll
  for (int nt = 0; nt < 6; nt++)
    bp[nt] = Bt + (size_t)(nt * 16 + l15) * K + kb;
  const size_t RA = (size_t)16 * K;

  #pragma unroll
  for (int kk = 0; kk < K; kk += 32) {
    bf16x8 a[2], b[6];
    #pragma unroll
    for (int s = 0; s < 2; s++) a[s] = *(const bf16x8*)(ap + s * RA + kk);
    #pragma unroll
    for (int nt = 0; nt < 6; nt++) b[nt] = *(const bf16x8*)(bp[nt] + kk);
    #pragma unroll
    for (int s = 0; s < 2; s++)
      #pragma unroll
      for (int nt = 0; nt < 6; nt++)
        acc[s][nt] = mfma16(a[s], b[nt], acc[s][nt]);
  }

  float ub3v = ub3[0];
  float u3v[6], b2v[6];
  #pragma unroll
  for (int nt = 0; nt < 6; nt++) {
    int col = nt * 16 + l15;
    u3v[nt] = U3[col];
    b2v[nt] = ub2[col];
  }
  #pragma unroll
  for (int s = 0; s < 2; s++) {
    #pragma unroll
    for (int r = 0; r < 4; r++) {
      float part = 0.0f;
      #pragma unroll
      for (int nt = 0; nt < 6; nt++)
        part += gelu_f(acc[s][nt][r] + b2v[nt]) * u3v[nt];
      #pragma unroll
      for (int d = 1; d < 16; d <<= 1) part += __shfl_xor(part, d);
      if (l15 == 0) {
        int m = m0 + s * 16 + ((lane >> 4) << 2) + r;
        unc[m] = 1.0f / (1.0f + expf(-(part + ub3v)));
      }
    }
  }
}

// ---------------- GCN aggregation, batch-fused ----------------
__global__ __launch_bounds__(384) void k_gcn_agg(
    const u16* __restrict__ xw, u16* __restrict__ Xb,
    const float* __restrict__ bias, const float* __restrict__ dinv,
    const int* __restrict__ offs, const int* __restrict__ insrc) {
  const size_t PLANE = (size_t)N_NODES * C_DIM;
  int t = threadIdx.x;
  int g = t / 96, l = t % 96;
  int n = blockIdx.x * 4 + g;
  int beg = offs[n], end = offs[n + 1];
  int c = 4 * l;
  const u16* base = xw + c;

  f32x4 a0 = {0,0,0,0}, a1 = {0,0,0,0}, a2 = {0,0,0,0}, a3 = {0,0,0,0};
  f32x4 a4 = {0,0,0,0}, a5 = {0,0,0,0}, a6 = {0,0,0,0}, a7 = {0,0,0,0};

  for (int e = beg; e < end; e++) {
    int i = insrc[e];
    float dv = dinv[i];
    const u16* rp = base + (size_t)i * C_DIM;
    ushort4 v0 = *(const ushort4*)(rp);
    ushort4 v1 = *(const ushort4*)(rp + PLANE);
    ushort4 v2 = *(const ushort4*)(rp + 2 * PLANE);
    ushort4 v3 = *(const ushort4*)(rp + 3 * PLANE);
    ushort4 v4 = *(const ushort4*)(rp + 4 * PLANE);
    ushort4 v5 = *(const ushort4*)(rp + 5 * PLANE);
    ushort4 v6 = *(const ushort4*)(rp + 6 * PLANE);
    ushort4 v7 = *(const ushort4*)(rp + 7 * PLANE);
    a0.x += dv * bf2f(v0.x); a0.y += dv * bf2f(v0.y); a0.z += dv * bf2f(v0.z); a0.w += dv * bf2f(v0.w);
    a1.x += dv * bf2f(v1.x); a1.y += dv * bf2f(v1.y); a1.z += dv * bf2f(v1.z); a1.w += dv * bf2f(v1.w);
    a2.x += dv * bf2f(v2.x); a2.y += dv * bf2f(v2.y); a2.z += dv * bf2f(v2.z); a2.w += dv * bf2f(v2.w);
    a3.x += dv * bf2f(v3.x); a3.y += dv * bf2f(v3.y); a3.z += dv * bf2f(v3.z); a3.w += dv * bf2f(v3.w);
    a4.x += dv * bf2f(v4.x); a4.y += dv * bf2f(v4.y); a4.z += dv * bf2f(v4.z); a4.w += dv * bf2f(v4.w);
    a5.x += dv * bf2f(v5.x); a5.y += dv * bf2f(v5.y); a5.z += dv * bf2f(v5.z); a5.w += dv * bf2f(v5.w);
    a6.x += dv * bf2f(v6.x); a6.y += dv * bf2f(v6.y); a6.z += dv * bf2f(v6.z); a6.w += dv * bf2f(v6.w);
    a7.x += dv * bf2f(v7.x); a7.y += dv * bf2f(v7.y); a7.z += dv * bf2f(v7.z); a7.w += dv * bf2f(v7.w);
  }

  float dn = dinv[n];
  float4 b4 = *(const float4*)(bias + c);
  size_t ob = (size_t)n * C_DIM + c;
  f32x4 av[8] = {a0, a1, a2, a3, a4, a5, a6, a7};
  #pragma unroll
  for (int b = 0; b < 8; b++) {
    size_t o = ob + (size_t)b * PLANE;
    ushort4 xo = *(ushort4*)(Xb + o);
    ushort4 xn;
    xn.x = f2bf(bf2f(xo.x) + fmaxf(dn * av[b].x + b4.x, 0.f));
    xn.y = f2bf(bf2f(xo.y) + fmaxf(dn * av[b].y + b4.y, 0.f));
    xn.z = f2bf(bf2f(xo.z) + fmaxf(dn * av[b].z + b4.z, 0.f));
    xn.w = f2bf(bf2f(xo.w) + fmaxf(dn * av[b].w + b4.w, 0.f));
    *(ushort4*)(Xb + o) = xn;
  }
}

// ---------------- out = fea * (1 + unc), float4 ----------------
__global__ __launch_bounds__(256) void k_final(
    const float* __restrict__ fea, const float* __restrict__ unc,
    float* __restrict__ out) {
  size_t i4 = (size_t)blockIdx.x * 256 + threadIdx.x;
  size_t idx = i4 * 4;
  if (idx >= (size_t)B_DIM * C_DIM * N_NODES) return;
  int b = (int)(idx / ((size_t)C_DIM * N_NODES));
  int n = (int)(idx & (N_NODES - 1));
  float4 f = *(const float4*)(fea + idx);
  float4 u = *(const float4*)(unc + (size_t)b * N_NODES + n);
  float4 o;
  o.x = f.x * (1.0f + u.x);
  o.y = f.y * (1.0f + u.y);
  o.z = f.z * (1.0f + u.z);
  o.w = f.w * (1.0f + u.w);
  *(float4*)(out + idx) = o;
}

extern "C" void kernel_launch(void* const* d_in, const int* in_sizes, int n_in,
                              void* d_out, int out_size, void* d_ws, size_t ws_size,
                              hipStream_t stream) {
  const float* fea = (const float*)d_in[0];
  const float* W1  = (const float*)d_in[1];
  const float* b1  = (const float*)d_in[2];
  const float* W2  = (const float*)d_in[3];
  const float* b2  = (const float*)d_in[4];
  const float* W3  = (const float*)d_in[5];
  const float* b3  = (const float*)d_in[6];
  const float* U1  = (const float*)d_in[7];
  const float* ub1 = (const float*)d_in[8];
  const float* U2  = (const float*)d_in[9];
  const float* ub2 = (const float*)d_in[10];
  const float* U3  = (const float*)d_in[11];
  const float* ub3 = (const float*)d_in[12];
  float* out = (float*)d_out;

  char* ws = (char*)d_ws;
  u16*   Xb   = (u16*)  (ws + 0);                       // 25165824
  u16*   XWb  = (u16*)  (ws + 25165824);                // 25165824
  u64*   pk   = (u64*)  (ws + 25165824);                // 1048576 (aliases XWb, pre-GEMM)
  u16*   h1b  = (u16*)  (ws + 25165824);                // 12582912 (aliases XWb, post-GCN)
  u16*   fh   = (u16*)  (ws + 50331648);                // 3145728
  u16*   fl   = (u16*)  (ws + 53477376);                // 3145728
  float* x2   = (float*)(ws + 56623104);                // 16384
  int*   tk   = (int*)  (ws + 56639488);                // 131072
  int*   deg  = (int*)  (ws + 56770560);                // 16384
  float* dinv = (float*)(ws + 56786944);                // 16384
  int*   offs = (int*)  (ws + 56803328);                // 16896
  int*   cnt  = (int*)  (ws + 56820224);                // 16384
  int*   insrc= (int*)  (ws + 56836608);                // 131072
  float* unc  = (float*)(ws + 56967680);                // 131072
  u16*   Wt1  = (u16*)  (ws + 57098752);                // 294912
  u16*   Wt2  = (u16*)  (ws + 57393664);                // 294912
  u16*   Wt3  = (u16*)  (ws + 57688576);                // 294912
  u16*   U1t  = (u16*)  (ws + 57983488);                // 147456
  u16*   U2t  = (u16*)  (ws + 58130944);                // 36864
  int*   flag = (int*)  (ws + 58167808);                // 16384

  // 0) weights -> transposed bf16
  k_prep_w<<<2088, 256, 0, stream>>>(W1, W2, W3, U1, U2, Wt1, Wt2, Wt3, U1t, U2t);
  // 1) transpose + mean -> Xb, fh/fl
  k_transpose_mean<<<dim3(N_NODES / 128, C_DIM / 32), dim3(32, 8), 0, stream>>>(
      fea, Xb, fh, fl);
  // 2) norms
  k_x2<<<N_NODES, 64, 0, stream>>>(fh, fl, x2);
  // 3) windowed distance top-8 (LDS-staged, zeroes deg/cnt), merge(+deg/flag),
  //    exact fallback (+deg)
  k_dist_win<<<256, 256, 0, stream>>>(fh, fl, x2, pk, deg, cnt);
  k_topk_merge<<<N_NODES / 256, 256, 0, stream>>>(pk, tk, flag, deg);
  k_fb<<<64, 256, 0, stream>>>(fh, fl, x2, flag, tk, deg);
  // 4) graph build
  k_scan<<<1, 256, 0, stream>>>(deg, offs, dinv);
  k_fill<<<E_TOT / 256, 256, 0, stream>>>(tk, offs, cnt, insrc);
  k_sort<<<N_NODES / 256, 256, 0, stream>>>(offs, insrc);
  // 5) three GCN layers (LDS-staged bf16 MFMA GEMM + batch-fused aggregation)
  const u16* Wl[3] = {Wt1, Wt2, Wt3};
  const float* bl[3] = {b1, b2, b3};
  for (int l = 0; l < 3; l++) {
    k_gemm_lds<3><<<dim3(M_ROWS / 128, 3), 256, 0, stream>>>(
        Xb, Wl[l], nullptr, XWb, M_ROWS, C_DIM, C_DIM);
    k_gcn_agg<<<N_NODES / 4, 384, 0, stream>>>(XWb, Xb, bl[l], dinv, offs, insrc);
  }
  // 6) MLP: h1 = gelu(Xb@U1+ub1) -> bf16; fused tail -> unc
  k_gemm_lds<1><<<dim3(M_ROWS / 128, 2), 256, 0, stream>>>(
      Xb, U1t, ub1, h1b, M_ROWS, 192, C_DIM);
  k_mlp2<<<M_ROWS / 128, 256, 0, stream>>>(h1b, U2t, ub2, U3, ub3, unc);
  // 7) output
  size_t tot = (size_t)B_DIM * C_DIM * N_NODES;
  k_final<<<(tot / 4 + 255) / 256, 256, 0, stream>>>(fea, unc, out);
}

// Round 11
// 281.088 us; speedup vs baseline: 1.4215x; 1.0291x over previous
//
#include <hip/hip_runtime.h>
#include <hip/hip_bf16.h>
#include <math.h>

#define N_NODES 4096
#define C_DIM   384
#define B_DIM   8
#define K_NB    8
#define E_TOT   (N_NODES * K_NB)     // 32768
#define M_ROWS  (B_DIM * N_NODES)    // 32768
#define NCHUNK  4                    // one partial list per wave of the patch block
#define SROW    40                   // dist-win LDS row stride in u16 (32 data + 8 pad)

typedef unsigned long long u64;
typedef unsigned short u16;
typedef __attribute__((ext_vector_type(8))) short bf16x8;
typedef __attribute__((ext_vector_type(4))) float f32x4;
#define KEY_INF 0xFFFFFFFFFFFFFFFFull

__device__ __forceinline__ u16 f2bf(float f) {
  unsigned u = __float_as_uint(f);
  u += 0x7FFFu + ((u >> 16) & 1u);
  return (u16)(u >> 16);
}
__device__ __forceinline__ float bf2f(u16 h) {
  return __uint_as_float((unsigned)h << 16);
}
__device__ __forceinline__ f32x4 mfma16(bf16x8 a, bf16x8 b, f32x4 c) {
  return __builtin_amdgcn_mfma_f32_16x16x32_bf16(a, b, c, 0, 0, 0);
}
// async global->LDS, 16B per lane; LDS dest = wave-uniform base + lane*16
__device__ __forceinline__ void gl_lds16(const u16* gp, u16* lp) {
  __builtin_amdgcn_global_load_lds(
      (const __attribute__((address_space(1))) unsigned int*)gp,
      (__attribute__((address_space(3))) unsigned int*)lp, 16, 0, 0);
}

__device__ __forceinline__ void ce(u64& a, u64& b) {
  u64 lo = a < b ? a : b;
  u64 hi = a < b ? b : a;
  a = lo; b = hi;
}
__device__ __forceinline__ void ins8(u64 key, u64 (&r)[8]) {
  if (key < r[7]) {
    #pragma unroll
    for (int i = 0; i < 8; i++) {
      u64 lo = key < r[i] ? key : r[i];
      u64 hi = key < r[i] ? r[i] : key;
      r[i] = lo; key = hi;
    }
  }
}
// merge two ascending sorted-8 lists -> ascending 8 smallest
__device__ __forceinline__ void merge8(u64 (&r)[8], const u64 (&o)[8]) {
  u64 c[8];
  #pragma unroll
  for (int i = 0; i < 8; i++) c[i] = r[i] < o[7 - i] ? r[i] : o[7 - i];
  ce(c[0], c[4]); ce(c[1], c[5]); ce(c[2], c[6]); ce(c[3], c[7]);
  ce(c[0], c[2]); ce(c[1], c[3]); ce(c[4], c[6]); ce(c[5], c[7]);
  ce(c[0], c[1]); ce(c[2], c[3]); ce(c[4], c[5]); ce(c[6], c[7]);
  #pragma unroll
  for (int i = 0; i < 8; i++) r[i] = c[i];
}

// ---------------- weight prep: transpose + bf16 ----------------
__global__ __launch_bounds__(256) void k_prep_w(
    const float* __restrict__ W1, const float* __restrict__ W2,
    const float* __restrict__ W3, const float* __restrict__ U1,
    const float* __restrict__ U2,
    u16* __restrict__ Wt1, u16* __restrict__ Wt2, u16* __restrict__ Wt3,
    u16* __restrict__ U1t, u16* __restrict__ U2t) {
  int idx = blockIdx.x * 256 + threadIdx.x;
  if (idx < 147456) {
    int n = idx / 384, k = idx % 384;
    Wt1[idx] = f2bf(W1[k * 384 + n]);
  } else if (idx < 294912) {
    int i = idx - 147456; int n = i / 384, k = i % 384;
    Wt2[i] = f2bf(W2[k * 384 + n]);
  } else if (idx < 442368) {
    int i = idx - 294912; int n = i / 384, k = i % 384;
    Wt3[i] = f2bf(W3[k * 384 + n]);
  } else if (idx < 516096) {
    int i = idx - 442368; int n = i / 384, k = i % 384;
    U1t[i] = f2bf(U1[k * 192 + n]);
  } else if (idx < 534528) {
    int i = idx - 516096; int n = i / 192, k = i % 192;
    U2t[i] = f2bf(U2[k * 96 + n]);
  }
}

// ---------------- transpose + batch mean -> Xb (bf16) + fh/fl ----------------
__global__ __launch_bounds__(256) void k_transpose_mean(
    const float* __restrict__ fea, u16* __restrict__ Xb,
    u16* __restrict__ fh, u16* __restrict__ fl) {
  __shared__ float tb[32][132];
  __shared__ float ac[32][132];
  int n0 = blockIdx.x * 128, c0 = blockIdx.y * 32;
  int tx = threadIdx.x, ty = threadIdx.y;   // (32,8)
  for (int i = ty; i < 32; i += 8) {
    #pragma unroll
    for (int e = 0; e < 4; e++) ac[i][tx * 4 + e] = 0.0f;
  }
  __syncthreads();
  for (int b = 0; b < B_DIM; b++) {
    for (int i = ty; i < 32; i += 8) {
      float4 v = *(const float4*)(fea +
          ((size_t)b * C_DIM + (c0 + i)) * N_NODES + n0 + tx * 4);
      *(float4*)&tb[i][tx * 4] = v;
      ac[i][tx * 4 + 0] += v.x;
      ac[i][tx * 4 + 1] += v.y;
      ac[i][tx * 4 + 2] += v.z;
      ac[i][tx * 4 + 3] += v.w;
    }
    __syncthreads();
    for (int rr = ty; rr < 128; rr += 8) {
      size_t o = ((size_t)b * N_NODES + (n0 + rr)) * C_DIM + c0 + tx;
      Xb[o] = f2bf(tb[tx][rr]);
    }
    __syncthreads();
  }
  for (int rr = ty; rr < 128; rr += 8) {
    float m = ac[tx][rr] * 0.125f;
    u16 h = f2bf(m);
    size_t o = (size_t)(n0 + rr) * C_DIM + c0 + tx;
    fh[o] = h;
    fl[o] = f2bf(m - bf2f(h));
  }
}

// ---------------- squared norms (from hi+lo) ----------------
__global__ __launch_bounds__(64) void k_x2(const u16* __restrict__ fh,
                                           const u16* __restrict__ fl,
                                           float* __restrict__ x2) {
  int n = blockIdx.x;
  int lane = threadIdx.x;
  const u16* rh = fh + (size_t)n * C_DIM;
  const u16* rl = fl + (size_t)n * C_DIM;
  float s = 0.0f;
  for (int c = lane; c < C_DIM; c += 64) {
    float v = bf2f(rh[c]) + bf2f(rl[c]);
    s += v * v;
  }
  for (int d = 32; d > 0; d >>= 1) s += __shfl_down(s, d);
  if (lane == 0) x2[n] = s;
}

// ---------------- windowed distance + top-8, LDS-staged per-patch block ----------------
__global__ __launch_bounds__(256) void k_dist_win(
    const u16* __restrict__ fh, const u16* __restrict__ fl,
    const float* __restrict__ x2, u64* __restrict__ pk,
    int* __restrict__ deg, int* __restrict__ cnt) {
  __shared__ u16 WH[400 * SROW];
  __shared__ u16 WL[400 * SROW];
  int t = threadIdx.x;
  int lane = t & 63, w = t >> 6;
  int p = blockIdx.x;
  int py = p >> 4, px = p & 15;
  int iy0 = py * 4, ix0 = px * 4;
  int l15 = lane & 15;
  int kb = (lane >> 4) * 8;

  if (p < 16) { deg[p * 256 + t] = 0; cnt[p * 256 + t] = 0; }

  int t0 = (w == 0) ? 0 : 7 + (w - 1) * 6;
  int nt = w ? 6 : 7;

  int jj[7]; float x2j[7]; int jy_[7], jx_[7];
  #pragma unroll
  for (int tt = 0; tt < 7; tt++) {
    int s = (t0 + tt) * 16 + l15;
    int sy = s / 20, sx = s - sy * 20;
    int jy = iy0 - 8 + sy, jx = ix0 - 8 + sx;
    bool v = (tt < nt) && ((unsigned)jy < 64u) && ((unsigned)jx < 64u);
    jj[tt] = v ? (jy * 64 + jx) : -1;
    jy_[tt] = jy; jx_[tt] = jx;
    x2j[tt] = v ? x2[jy * 64 + jx] : 0.0f;
  }
  int pr = 168 + (l15 >> 2) * 20 + (l15 & 3);

  int seg = t & 3;
  int rb = t >> 2;

  f32x4 acc[7];
  #pragma unroll
  for (int tt = 0; tt < 7; tt++) acc[tt] = (f32x4){0.f, 0.f, 0.f, 0.f};

  for (int kc = 0; kc < 12; kc++) {
    int k0 = kc * 32;
    __syncthreads();
    #pragma unroll
    for (int it = 0; it < 7; it++) {
      int r = rb + 64 * it;
      if (r < 400) {
        int sy = r / 20, sx = r - sy * 20;
        int jy = iy0 - 8 + sy, jx = ix0 - 8 + sx;
        int j = (((unsigned)jy < 64u) && ((unsigned)jx < 64u)) ? jy * 64 + jx : 0;
        size_t src = (size_t)j * C_DIM + k0 + seg * 8;
        *(bf16x8*)&WH[r * SROW + seg * 8] = *(const bf16x8*)(fh + src);
        *(bf16x8*)&WL[r * SROW + seg * 8] = *(const bf16x8*)(fl + src);
      }
    }
    __syncthreads();
    bf16x8 aH = *(const bf16x8*)&WH[pr * SROW + kb];
    bf16x8 aL = *(const bf16x8*)&WL[pr * SROW + kb];
    #pragma unroll
    for (int tt = 0; tt < 7; tt++) {
      int row = (t0 + tt) * 16 + l15;
      bf16x8 bH = *(const bf16x8*)&WH[row * SROW + kb];
      bf16x8 bL = *(const bf16x8*)&WL[row * SROW + kb];
      acc[tt] = mfma16(aH, bH, acc[tt]);
      acc[tt] = mfma16(aL, bH, acc[tt]);
      acc[tt] = mfma16(aH, bL, acc[tt]);
    }
  }

  #pragma unroll
  for (int r = 0; r < 4; r++) {
    int r16 = ((lane >> 4) << 2) + r;
    int iy = iy0 + (r16 >> 2), ix = ix0 + (r16 & 3);
    int i = iy * 64 + ix;
    float x2i = x2[i];
    u64 top[8];
    #pragma unroll
    for (int q = 0; q < 8; q++) top[q] = KEY_INF;
    #pragma unroll
    for (int tt = 0; tt < 7; tt++) {
      float d2 = x2i + x2j[tt] - 2.0f * acc[tt][r];
      float fd = sqrtf(fmaxf(d2, 0.0f));
      float dy = (float)(iy - jy_[tt]), dx = (float)(ix - jx_[tt]);
      float sd = sqrtf(dy * dy + dx * dx);
      float comb = 0.7f * sd + 0.3f * fd;
      u64 key = (jj[tt] >= 0)
                    ? (((u64)__float_as_uint(comb) << 12) | (u64)jj[tt])
                    : KEY_INF;
      ins8(key, top);
    }
    #pragma unroll
    for (int d = 1; d < 16; d <<= 1) {
      u64 o[8];
      #pragma unroll
      for (int q = 0; q < 8; q++) o[q] = __shfl_xor(top[q], d);
      merge8(top, o);
    }
    if (l15 == 0) {
      #pragma unroll
      for (int q = 0; q < 8; q++)
        pk[((size_t)w * N_NODES + i) * 8 + q] = top[q];
    }
  }
}

// ---------------- merge 4 partial lists; count degrees; flag fallback rows ----------------
__global__ __launch_bounds__(256) void k_topk_merge(
    const u64* __restrict__ pk, int* __restrict__ tk, int* __restrict__ flag,
    int* __restrict__ deg) {
  int n = blockIdx.x * 256 + threadIdx.x;
  if (n >= N_NODES) return;
  u64 r[8];
  #pragma unroll
  for (int q = 0; q < 8; q++) r[q] = KEY_INF;
  for (int c = 0; c < NCHUNK; c++) {
    const u64* lst = pk + ((size_t)c * N_NODES + n) * 8;
    #pragma unroll
    for (int q = 0; q < 8; q++) {
      u64 key = lst[q];
      if (key >= r[7]) break;
      ins8(key, r);
    }
  }
  float c8 = __uint_as_float((unsigned)(r[7] >> 12));
  int fl = (c8 > 6.28f) ? 1 : 0;
  flag[n] = fl;
  #pragma unroll
  for (int o = 0; o < 8; o++) {
    int idx = (int)(r[o] & 0xFFF);
    tk[n * 8 + o] = idx;
    if (!fl) atomicAdd(&deg[idx], 1);
  }
}

// ---------------- exact fp32 full-scan fallback for flagged rows (+deg) ----------------
__global__ __launch_bounds__(256) void k_fb(
    const u16* __restrict__ fh, const u16* __restrict__ fl,
    const float* __restrict__ x2, const int* __restrict__ flag,
    int* __restrict__ tk, int* __restrict__ deg) {
  int w = threadIdx.x >> 6, lane = threadIdx.x & 63;
  for (int rr = 0; rr < 16; rr++) {
    int n = blockIdx.x * 64 + w * 16 + rr;
    if (!flag[n]) continue;
    u64 top[8];
    #pragma unroll
    for (int q = 0; q < 8; q++) top[q] = KEY_INF;
    float x2i = x2[n];
    int iy = n >> 6, ix = n & 63;
    const u16* rh = fh + (size_t)n * C_DIM;
    const u16* rl = fl + (size_t)n * C_DIM;
    for (int jb = 0; jb < N_NODES; jb += 64) {
      int j = jb + lane;
      const u16* ch = fh + (size_t)j * C_DIM;
      const u16* cl = fl + (size_t)j * C_DIM;
      float dot = 0.0f;
      for (int k2 = 0; k2 < C_DIM; k2++)
        dot += (bf2f(rh[k2]) + bf2f(rl[k2])) * (bf2f(ch[k2]) + bf2f(cl[k2]));
      float d2 = x2i + x2[j] - 2.0f * dot;
      float fd = sqrtf(fmaxf(d2, 0.0f));
      float dy = (float)(iy - (j >> 6)), dx = (float)(ix - (j & 63));
      float sd = sqrtf(dy * dy + dx * dx);
      float comb = 0.7f * sd + 0.3f * fd;
      ins8(((u64)__float_as_uint(comb) << 12) | (u64)j, top);
    }
    #pragma unroll
    for (int d = 1; d < 64; d <<= 1) {
      u64 o[8];
      #pragma unroll
      for (int q = 0; q < 8; q++) o[q] = __shfl_xor(top[q], d);
      merge8(top, o);
    }
    if (lane == 0) {
      #pragma unroll
      for (int q = 0; q < 8; q++) {
        int idx = (int)(top[q] & 0xFFF);
        tk[n * 8 + q] = idx;
        atomicAdd(&deg[idx], 1);
      }
    }
  }
}

// ---------------- exclusive scan (4096) + dinv ----------------
__global__ __launch_bounds__(256) void k_scan(const int* __restrict__ deg,
                                              int* __restrict__ offs,
                                              float* __restrict__ dinv) {
  __shared__ int ps[256];
  int t = threadIdx.x;
  int base = t * 16;
  int loc[16]; int s = 0;
  for (int i = 0; i < 16; i++) { int d = deg[base + i]; loc[i] = s; s += d; }
  ps[t] = s;
  __syncthreads();
  for (int d = 1; d < 256; d <<= 1) {
    int add = (t >= d) ? ps[t - d] : 0;
    __syncthreads();
    ps[t] += add;
    __syncthreads();
  }
  int cbase = (t == 0) ? 0 : ps[t - 1];
  for (int i = 0; i < 16; i++) offs[base + i] = cbase + loc[i];
  if (t == 255) offs[N_NODES] = ps[255];
  for (int i = 0; i < 16; i++)
    dinv[base + i] = 1.0f / sqrtf((float)deg[base + i]);
}

// ---------------- CSR fill ----------------
__global__ __launch_bounds__(256) void k_fill(const int* __restrict__ tk,
                                              const int* __restrict__ offs,
                                              int* __restrict__ cnt,
                                              int* __restrict__ insrc) {
  int e = blockIdx.x * 256 + threadIdx.x;
  if (e >= E_TOT) return;
  int i = e >> 3;
  int n = tk[e];
  int pos = offs[n] + atomicAdd(&cnt[n], 1);
  insrc[pos] = i;
}

// ---------------- per-node sort (determinism) ----------------
__global__ __launch_bounds__(256) void k_sort(const int* __restrict__ offs,
                                              int* __restrict__ insrc) {
  int n = blockIdx.x * 256 + threadIdx.x;
  if (n >= N_NODES) return;
  int beg = offs[n], end = offs[n + 1];
  for (int a = beg + 1; a < end; a++) {
    int v = insrc[a]; int p = a;
    while (p > beg && insrc[p - 1] > v) { insrc[p] = insrc[p - 1]; p--; }
    insrc[p] = v;
  }
}

// ---------------- LDS-staged bf16 MFMA GEMM via global_load_lds (m97 structure) ----------------
// C[M,N] = A[M,K] @ Bt[N,K]^T, 128x128 tile, BK=32, 4 waves 2x2 (64x64 each).
// Linear LDS [128][32]; each wave async-stages its 32 rows of A and B (2+2
// 1KB chunks). 2 barriers per K-step; ~5 blocks/CU gives wave-level overlap.
__device__ __forceinline__ float gelu_f(float x) {
  const float k0 = 0.7978845608028654f;  // sqrt(2/pi)
  float x3 = x * x * x;
  return 0.5f * x * (1.0f + tanhf(k0 * (x + 0.044715f * x3)));
}

template <int EPI>  // 1 = bias+gelu, 3 = plain; bf16 out
__global__ __launch_bounds__(256) void k_gemm_lds(
    const u16* __restrict__ A, const u16* __restrict__ Bt,
    const float* __restrict__ bias, u16* __restrict__ Cout,
    int M, int N, int K) {
  __shared__ u16 As[128 * 32];
  __shared__ u16 Bs[128 * 32];
  int t = threadIdx.x, lane = t & 63, w = t >> 6;
  int m0 = blockIdx.x * 128;
  int n0 = blockIdx.y * 128;
  int l15 = lane & 15;
  int kg = lane >> 4;
  int wr = (w >> 1) * 64, wc = (w & 1) * 64;

  // staging: wave w covers tile rows w*32 .. w*32+31 (two 16-row chunks);
  // lane l -> row chunkbase + (l>>2), 16B segment (l&3)
  int srow = w * 32 + (lane >> 2);
  int scol = (lane & 3) * 8;
  const u16* gA0 = A + (size_t)(m0 + srow) * K + scol;
  const u16* gA1 = A + (size_t)(m0 + srow + 16) * K + scol;
  int br0 = n0 + srow;      br0 = (br0 < N) ? br0 : 0;
  int br1 = n0 + srow + 16; br1 = (br1 < N) ? br1 : 0;
  const u16* gB0 = Bt + (size_t)br0 * K + scol;
  const u16* gB1 = Bt + (size_t)br1 * K + scol;
  u16* lA0 = &As[(w * 32) * 32];
  u16* lA1 = &As[(w * 32 + 16) * 32];
  u16* lB0 = &Bs[(w * 32) * 32];
  u16* lB1 = &Bs[(w * 32 + 16) * 32];

  f32x4 acc[4][4];
  #pragma unroll
  for (int s = 0; s < 4; s++)
    #pragma unroll
    for (int nt = 0; nt < 4; nt++) acc[s][nt] = (f32x4){0.f, 0.f, 0.f, 0.f};

  for (int kt = 0; kt < K; kt += 32) {
    __syncthreads();              // prev tile's reads complete
    gl_lds16(gA0 + kt, lA0);
    gl_lds16(gA1 + kt, lA1);
    gl_lds16(gB0 + kt, lB0);
    gl_lds16(gB1 + kt, lB1);
    __syncthreads();              // vmcnt(0) drain -> tile resident
    bf16x8 a[4], b[4];
    #pragma unroll
    for (int s = 0; s < 4; s++)
      a[s] = *(const bf16x8*)&As[(wr + s * 16 + l15) * 32 + kg * 8];
    #pragma unroll
    for (int nt = 0; nt < 4; nt++)
      b[nt] = *(const bf16x8*)&Bs[(wc + nt * 16 + l15) * 32 + kg * 8];
    #pragma unroll
    for (int s = 0; s < 4; s++)
      #pragma unroll
      for (int nt = 0; nt < 4; nt++)
        acc[s][nt] = mfma16(a[s], b[nt], acc[s][nt]);
  }

  #pragma unroll
  for (int s = 0; s < 4; s++) {
    int rbase = m0 + wr + s * 16 + ((lane >> 4) << 2);
    #pragma unroll
    for (int nt = 0; nt < 4; nt++) {
      int n = n0 + wc + nt * 16 + l15;
      if (n >= N) continue;
      float bb = (EPI == 1) ? bias[n] : 0.0f;
      #pragma unroll
      for (int r = 0; r < 4; r++) {
        int m = rbase + r;
        float v = acc[s][nt][r];
        if (EPI == 1) { v += bb; v = gelu_f(v); }
        Cout[(size_t)m * N + n] = f2bf(v);
      }
    }
  }
}

// ---------------- fused MLP tail: unc = sigmoid(gelu(h1@U2+ub2)@U3+ub3) ----------------
__global__ __launch_bounds__(256) void k_mlp2(
    const u16* __restrict__ A, const u16* __restrict__ Bt,
    const float* __restrict__ ub2, const float* __restrict__ U3,
    const float* __restrict__ ub3, float* __restrict__ unc) {
  const int K = 192;
  int t = threadIdx.x, lane = t & 63, w = t >> 6;
  int m0 = blockIdx.x * 128 + w * 32;
  int l15 = lane & 15;
  int kb = (lane >> 4) * 8;

  f32x4 acc[2][6];
  #pragma unroll
  for (int s = 0; s < 2; s++)
    #pragma unroll
    for (int nt = 0; nt < 6; nt++) acc[s][nt] = (f32x4){0.f, 0.f, 0.f, 0.f};

  const u16* ap = A + (size_t)(m0 + l15) * K + kb;
  const u16* bp[6];
  #pragma unroll
  for (int nt = 0; nt < 6; nt++)
    bp[nt] = Bt + (size_t)(nt * 16 + l15) * K + kb;
  const size_t RA = (size_t)16 * K;

  #pragma unroll
  for (int kk = 0; kk < K; kk += 32) {
    bf16x8 a[2], b[6];
    #pragma unroll
    for (int s = 0; s < 2; s++) a[s] = *(const bf16x8*)(ap + s * RA + kk);
    #pragma unroll
    for (int nt = 0; nt < 6; nt++) b[nt] = *(const bf16x8*)(bp[nt] + kk);
    #pragma unroll
    for (int s = 0; s < 2; s++)
      #pragma unroll
      for (int nt = 0; nt < 6; nt++)
        acc[s][nt] = mfma16(a[s], b[nt], acc[s][nt]);
  }

  float ub3v = ub3[0];
  float u3v[6], b2v[6];
  #pragma unroll
  for (int nt = 0; nt < 6; nt++) {
    int col = nt * 16 + l15;
    u3v[nt] = U3[col];
    b2v[nt] = ub2[col];
  }
  #pragma unroll
  for (int s = 0; s < 2; s++) {
    #pragma unroll
    for (int r = 0; r < 4; r++) {
      float part = 0.0f;
      #pragma unroll
      for (int nt = 0; nt < 6; nt++)
        part += gelu_f(acc[s][nt][r] + b2v[nt]) * u3v[nt];
      #pragma unroll
      for (int d = 1; d < 16; d <<= 1) part += __shfl_xor(part, d);
      if (l15 == 0) {
        int m = m0 + s * 16 + ((lane >> 4) << 2) + r;
        unc[m] = 1.0f / (1.0f + expf(-(part + ub3v)));
      }
    }
  }
}

// ---------------- GCN aggregation: 48-lane group = (node, 4-plane half),
// 8 channels/lane via 16B gathers; 1024 blocks keep 6144-wave TLP ----------------
__global__ __launch_bounds__(384) void k_gcn_agg(
    const u16* __restrict__ xw, u16* __restrict__ Xb,
    const float* __restrict__ bias, const float* __restrict__ dinv,
    const int* __restrict__ offs, const int* __restrict__ insrc) {
  const size_t PLANE = (size_t)N_NODES * C_DIM;
  int t = threadIdx.x;
  int g = t / 48, l = t % 48;       // 8 groups of 48 lanes
  int slot = blockIdx.x * 8 + g;    // 8192 slots = 4096 nodes x 2 halves
  int n = slot >> 1;
  int hb = (slot & 1) * 4;          // plane base (0 or 4)
  int beg = offs[n], end = offs[n + 1];
  int c0 = l * 8;
  const u16* base = xw + c0 + (size_t)hb * PLANE;

  float a0[8] = {}, a1[8] = {}, a2[8] = {}, a3[8] = {};
  for (int e = beg; e < end; e++) {
    int i = insrc[e];
    float dv = dinv[i];
    const u16* rp = base + (size_t)i * C_DIM;
    bf16x8 v0 = *(const bf16x8*)(rp);
    bf16x8 v1 = *(const bf16x8*)(rp + PLANE);
    bf16x8 v2 = *(const bf16x8*)(rp + 2 * PLANE);
    bf16x8 v3 = *(const bf16x8*)(rp + 3 * PLANE);
    #pragma unroll
    for (int ch = 0; ch < 8; ch++) {
      a0[ch] += dv * bf2f((u16)v0[ch]);
      a1[ch] += dv * bf2f((u16)v1[ch]);
      a2[ch] += dv * bf2f((u16)v2[ch]);
      a3[ch] += dv * bf2f((u16)v3[ch]);
    }
  }

  float dn = dinv[n];
  float bv[8];
  #pragma unroll
  for (int ch = 0; ch < 8; ch++) bv[ch] = bias[c0 + ch];
  size_t ob = (size_t)n * C_DIM + c0 + (size_t)hb * PLANE;
  u16* xp0 = Xb + ob;
  u16* xp1 = Xb + ob + PLANE;
  u16* xp2 = Xb + ob + 2 * PLANE;
  u16* xp3 = Xb + ob + 3 * PLANE;
  bf16x8 xo0 = *(const bf16x8*)xp0, xo1 = *(const bf16x8*)xp1;
  bf16x8 xo2 = *(const bf16x8*)xp2, xo3 = *(const bf16x8*)xp3;
  bf16x8 xn0, xn1, xn2, xn3;
  #pragma unroll
  for (int ch = 0; ch < 8; ch++) {
    xn0[ch] = (short)f2bf(bf2f((u16)xo0[ch]) + fmaxf(dn * a0[ch] + bv[ch], 0.f));
    xn1[ch] = (short)f2bf(bf2f((u16)xo1[ch]) + fmaxf(dn * a1[ch] + bv[ch], 0.f));
    xn2[ch] = (short)f2bf(bf2f((u16)xo2[ch]) + fmaxf(dn * a2[ch] + bv[ch], 0.f));
    xn3[ch] = (short)f2bf(bf2f((u16)xo3[ch]) + fmaxf(dn * a3[ch] + bv[ch], 0.f));
  }
  *(bf16x8*)xp0 = xn0;
  *(bf16x8*)xp1 = xn1;
  *(bf16x8*)xp2 = xn2;
  *(bf16x8*)xp3 = xn3;
}

// ---------------- out = fea * (1 + unc), float4 ----------------
__global__ __launch_bounds__(256) void k_final(
    const float* __restrict__ fea, const float* __restrict__ unc,
    float* __restrict__ out) {
  size_t i4 = (size_t)blockIdx.x * 256 + threadIdx.x;
  size_t idx = i4 * 4;
  if (idx >= (size_t)B_DIM * C_DIM * N_NODES) return;
  int b = (int)(idx / ((size_t)C_DIM * N_NODES));
  int n = (int)(idx & (N_NODES - 1));
  float4 f = *(const float4*)(fea + idx);
  float4 u = *(const float4*)(unc + (size_t)b * N_NODES + n);
  float4 o;
  o.x = f.x * (1.0f + u.x);
  o.y = f.y * (1.0f + u.y);
  o.z = f.z * (1.0f + u.z);
  o.w = f.w * (1.0f + u.w);
  *(float4*)(out + idx) = o;
}

extern "C" void kernel_launch(void* const* d_in, const int* in_sizes, int n_in,
                              void* d_out, int out_size, void* d_ws, size_t ws_size,
                              hipStream_t stream) {
  const float* fea = (const float*)d_in[0];
  const float* W1  = (const float*)d_in[1];
  const float* b1  = (const float*)d_in[2];
  const float* W2  = (const float*)d_in[3];
  const float* b2  = (const float*)d_in[4];
  const float* W3  = (const float*)d_in[5];
  const float* b3  = (const float*)d_in[6];
  const float* U1  = (const float*)d_in[7];
  const float* ub1 = (const float*)d_in[8];
  const float* U2  = (const float*)d_in[9];
  const float* ub2 = (const float*)d_in[10];
  const float* U3  = (const float*)d_in[11];
  const float* ub3 = (const float*)d_in[12];
  float* out = (float*)d_out;

  char* ws = (char*)d_ws;
  u16*   Xb   = (u16*)  (ws + 0);                       // 25165824
  u16*   XWb  = (u16*)  (ws + 25165824);                // 25165824
  u64*   pk   = (u64*)  (ws + 25165824);                // 1048576 (aliases XWb, pre-GEMM)
  u16*   h1b  = (u16*)  (ws + 25165824);                // 12582912 (aliases XWb, post-GCN)
  u16*   fh   = (u16*)  (ws + 50331648);                // 3145728
  u16*   fl   = (u16*)  (ws + 53477376);                // 3145728
  float* x2   = (float*)(ws + 56623104);                // 16384
  int*   tk   = (int*)  (ws + 56639488);                // 131072
  int*   deg  = (int*)  (ws + 56770560);                // 16384
  float* dinv = (float*)(ws + 56786944);                // 16384
  int*   offs = (int*)  (ws + 56803328);                // 16896
  int*   cnt  = (int*)  (ws + 56820224);                // 16384
  int*   insrc= (int*)  (ws + 56836608);                // 131072
  float* unc  = (float*)(ws + 56967680);                // 131072
  u16*   Wt1  = (u16*)  (ws + 57098752);                // 294912
  u16*   Wt2  = (u16*)  (ws + 57393664);                // 294912
  u16*   Wt3  = (u16*)  (ws + 57688576);                // 294912
  u16*   U1t  = (u16*)  (ws + 57983488);                // 147456
  u16*   U2t  = (u16*)  (ws + 58130944);                // 36864
  int*   flag = (int*)  (ws + 58167808);                // 16384

  // 0) weights -> transposed bf16
  k_prep_w<<<2088, 256, 0, stream>>>(W1, W2, W3, U1, U2, Wt1, Wt2, Wt3, U1t, U2t);
  // 1) transpose + mean -> Xb, fh/fl
  k_transpose_mean<<<dim3(N_NODES / 128, C_DIM / 32), dim3(32, 8), 0, stream>>>(
      fea, Xb, fh, fl);
  // 2) norms
  k_x2<<<N_NODES, 64, 0, stream>>>(fh, fl, x2);
  // 3) windowed distance top-8 (LDS-staged, zeroes deg/cnt), merge(+deg/flag),
  //    exact fallback (+deg)
  k_dist_win<<<256, 256, 0, stream>>>(fh, fl, x2, pk, deg, cnt);
  k_topk_merge<<<N_NODES / 256, 256, 0, stream>>>(pk, tk, flag, deg);
  k_fb<<<64, 256, 0, stream>>>(fh, fl, x2, flag, tk, deg);
  // 4) graph build
  k_scan<<<1, 256, 0, stream>>>(deg, offs, dinv);
  k_fill<<<E_TOT / 256, 256, 0, stream>>>(tk, offs, cnt, insrc);
  k_sort<<<N_NODES / 256, 256, 0, stream>>>(offs, insrc);
  // 5) three GCN layers (global_load_lds GEMM + batch-fused aggregation)
  const u16* Wl[3] = {Wt1, Wt2, Wt3};
  const float* bl[3] = {b1, b2, b3};
  for (int l = 0; l < 3; l++) {
    k_gemm_lds<3><<<dim3(M_ROWS / 128, 3), 256, 0, stream>>>(
        Xb, Wl[l], nullptr, XWb, M_ROWS, C_DIM, C_DIM);
    k_gcn_agg<<<N_NODES / 4, 384, 0, stream>>>(XWb, Xb, bl[l], dinv, offs, insrc);
  }
  // 6) MLP: h1 = gelu(Xb@U1+ub1) -> bf16; fused tail -> unc
  k_gemm_lds<1><<<dim3(M_ROWS / 128, 2), 256, 0, stream>>>(
      Xb, U1t, ub1, h1b, M_ROWS, 192, C_DIM);
  k_mlp2<<<M_ROWS / 128, 256, 0, stream>>>(h1b, U2t, ub2, U3, ub3, unc);
  // 7) output
  size_t tot = (size_t)B_DIM * C_DIM * N_NODES;
  k_final<<<(tot / 4 + 255) / 256, 256, 0, stream>>>(fea, unc, out);
}

// Round 12
// 273.448 us; speedup vs baseline: 1.4613x; 1.0279x over previous
//
#include <hip/hip_runtime.h>
#include <hip/hip_bf16.h>
#include <math.h>

#define N_NODES 4096
#define C_DIM   384
#define B_DIM   8
#define K_NB    8
#define E_TOT   (N_NODES * K_NB)     // 32768
#define M_ROWS  (B_DIM * N_NODES)    // 32768
#define NCHUNK  4                    // one partial list per wave of the patch block
#define SROW    40                   // dist-win LDS row stride in u16 (32 data + 8 pad)

typedef unsigned long long u64;
typedef unsigned short u16;
typedef __attribute__((ext_vector_type(8))) short bf16x8;
typedef __attribute__((ext_vector_type(4))) float f32x4;
#define KEY_INF 0xFFFFFFFFFFFFFFFFull

__device__ __forceinline__ u16 f2bf(float f) {
  unsigned u = __float_as_uint(f);
  u += 0x7FFFu + ((u >> 16) & 1u);
  return (u16)(u >> 16);
}
__device__ __forceinline__ float bf2f(u16 h) {
  return __uint_as_float((unsigned)h << 16);
}
__device__ __forceinline__ f32x4 mfma16(bf16x8 a, bf16x8 b, f32x4 c) {
  return __builtin_amdgcn_mfma_f32_16x16x32_bf16(a, b, c, 0, 0, 0);
}
// async global->LDS, 16B per lane; LDS dest = wave-uniform base + lane*16
__device__ __forceinline__ void gl_lds16(const u16* gp, u16* lp) {
  __builtin_amdgcn_global_load_lds(
      (const __attribute__((address_space(1))) unsigned int*)gp,
      (__attribute__((address_space(3))) unsigned int*)lp, 16, 0, 0);
}

__device__ __forceinline__ void ce(u64& a, u64& b) {
  u64 lo = a < b ? a : b;
  u64 hi = a < b ? b : a;
  a = lo; b = hi;
}
__device__ __forceinline__ void ins8(u64 key, u64 (&r)[8]) {
  if (key < r[7]) {
    #pragma unroll
    for (int i = 0; i < 8; i++) {
      u64 lo = key < r[i] ? key : r[i];
      u64 hi = key < r[i] ? r[i] : key;
      r[i] = lo; key = hi;
    }
  }
}
// merge two ascending sorted-8 lists -> ascending 8 smallest
__device__ __forceinline__ void merge8(u64 (&r)[8], const u64 (&o)[8]) {
  u64 c[8];
  #pragma unroll
  for (int i = 0; i < 8; i++) c[i] = r[i] < o[7 - i] ? r[i] : o[7 - i];
  ce(c[0], c[4]); ce(c[1], c[5]); ce(c[2], c[6]); ce(c[3], c[7]);
  ce(c[0], c[2]); ce(c[1], c[3]); ce(c[4], c[6]); ce(c[5], c[7]);
  ce(c[0], c[1]); ce(c[2], c[3]); ce(c[4], c[5]); ce(c[6], c[7]);
  #pragma unroll
  for (int i = 0; i < 8; i++) r[i] = c[i];
}

// ---------------- weight prep: transpose + bf16 ----------------
__global__ __launch_bounds__(256) void k_prep_w(
    const float* __restrict__ W1, const float* __restrict__ W2,
    const float* __restrict__ W3, const float* __restrict__ U1,
    const float* __restrict__ U2,
    u16* __restrict__ Wt1, u16* __restrict__ Wt2, u16* __restrict__ Wt3,
    u16* __restrict__ U1t, u16* __restrict__ U2t) {
  int idx = blockIdx.x * 256 + threadIdx.x;
  if (idx < 147456) {
    int n = idx / 384, k = idx % 384;
    Wt1[idx] = f2bf(W1[k * 384 + n]);
  } else if (idx < 294912) {
    int i = idx - 147456; int n = i / 384, k = i % 384;
    Wt2[i] = f2bf(W2[k * 384 + n]);
  } else if (idx < 442368) {
    int i = idx - 294912; int n = i / 384, k = i % 384;
    Wt3[i] = f2bf(W3[k * 384 + n]);
  } else if (idx < 516096) {
    int i = idx - 442368; int n = i / 384, k = i % 384;
    U1t[i] = f2bf(U1[k * 192 + n]);
  } else if (idx < 534528) {
    int i = idx - 516096; int n = i / 192, k = i % 192;
    U2t[i] = f2bf(U2[k * 96 + n]);
  }
}

// ---------------- transpose + batch mean -> Xb (bf16) + fh/fl, 16B writes ----------------
__global__ __launch_bounds__(256) void k_transpose_mean(
    const float* __restrict__ fea, u16* __restrict__ Xb,
    u16* __restrict__ fh, u16* __restrict__ fl) {
  __shared__ float tb[32][132];
  __shared__ float ac[32][132];
  int n0 = blockIdx.x * 128, c0 = blockIdx.y * 32;
  int tx = threadIdx.x, ty = threadIdx.y;   // (32,8)
  int flat = ty * 32 + tx;
  int g = flat & 3;            // channel group of 8
  int r2 = flat >> 2;          // row 0..63
  for (int i = ty; i < 32; i += 8) {
    #pragma unroll
    for (int e = 0; e < 4; e++) ac[i][tx * 4 + e] = 0.0f;
  }
  __syncthreads();
  for (int b = 0; b < B_DIM; b++) {
    for (int i = ty; i < 32; i += 8) {
      float4 v = *(const float4*)(fea +
          ((size_t)b * C_DIM + (c0 + i)) * N_NODES + n0 + tx * 4);
      *(float4*)&tb[i][tx * 4] = v;
      ac[i][tx * 4 + 0] += v.x;
      ac[i][tx * 4 + 1] += v.y;
      ac[i][tx * 4 + 2] += v.z;
      ac[i][tx * 4 + 3] += v.w;
    }
    __syncthreads();
    #pragma unroll
    for (int half = 0; half < 2; half++) {
      int r = r2 + 64 * half;
      bf16x8 v;
      #pragma unroll
      for (int cc = 0; cc < 8; cc++) v[cc] = (short)f2bf(tb[g * 8 + cc][r]);
      *(bf16x8*)&Xb[((size_t)b * N_NODES + n0 + r) * C_DIM + c0 + g * 8] = v;
    }
    __syncthreads();
  }
  #pragma unroll
  for (int half = 0; half < 2; half++) {
    int r = r2 + 64 * half;
    bf16x8 vh, vl;
    #pragma unroll
    for (int cc = 0; cc < 8; cc++) {
      float m = ac[g * 8 + cc][r] * 0.125f;
      u16 h = f2bf(m);
      vh[cc] = (short)h;
      vl[cc] = (short)f2bf(m - bf2f(h));
    }
    size_t o = (size_t)(n0 + r) * C_DIM + c0 + g * 8;
    *(bf16x8*)&fh[o] = vh;
    *(bf16x8*)&fl[o] = vl;
  }
}

// ---------------- squared norms (from hi+lo) ----------------
__global__ __launch_bounds__(64) void k_x2(const u16* __restrict__ fh,
                                           const u16* __restrict__ fl,
                                           float* __restrict__ x2) {
  int n = blockIdx.x;
  int lane = threadIdx.x;
  const u16* rh = fh + (size_t)n * C_DIM;
  const u16* rl = fl + (size_t)n * C_DIM;
  float s = 0.0f;
  for (int c = lane; c < C_DIM; c += 64) {
    float v = bf2f(rh[c]) + bf2f(rl[c]);
    s += v * v;
  }
  for (int d = 32; d > 0; d >>= 1) s += __shfl_down(s, d);
  if (lane == 0) x2[n] = s;
}

// ---------------- windowed distance + top-8, LDS-staged per-patch block ----------------
__global__ __launch_bounds__(256) void k_dist_win(
    const u16* __restrict__ fh, const u16* __restrict__ fl,
    const float* __restrict__ x2, u64* __restrict__ pk,
    int* __restrict__ deg, int* __restrict__ cnt) {
  __shared__ u16 WH[400 * SROW];
  __shared__ u16 WL[400 * SROW];
  int t = threadIdx.x;
  int lane = t & 63, w = t >> 6;
  int p = blockIdx.x;
  int py = p >> 4, px = p & 15;
  int iy0 = py * 4, ix0 = px * 4;
  int l15 = lane & 15;
  int kb = (lane >> 4) * 8;

  if (p < 16) { deg[p * 256 + t] = 0; cnt[p * 256 + t] = 0; }

  int t0 = (w == 0) ? 0 : 7 + (w - 1) * 6;
  int nt = w ? 6 : 7;

  int jj[7]; float x2j[7]; int jy_[7], jx_[7];
  #pragma unroll
  for (int tt = 0; tt < 7; tt++) {
    int s = (t0 + tt) * 16 + l15;
    int sy = s / 20, sx = s - sy * 20;
    int jy = iy0 - 8 + sy, jx = ix0 - 8 + sx;
    bool v = (tt < nt) && ((unsigned)jy < 64u) && ((unsigned)jx < 64u);
    jj[tt] = v ? (jy * 64 + jx) : -1;
    jy_[tt] = jy; jx_[tt] = jx;
    x2j[tt] = v ? x2[jy * 64 + jx] : 0.0f;
  }
  int pr = 168 + (l15 >> 2) * 20 + (l15 & 3);

  int seg = t & 3;
  int rb = t >> 2;

  f32x4 acc[7];
  #pragma unroll
  for (int tt = 0; tt < 7; tt++) acc[tt] = (f32x4){0.f, 0.f, 0.f, 0.f};

  for (int kc = 0; kc < 12; kc++) {
    int k0 = kc * 32;
    __syncthreads();
    #pragma unroll
    for (int it = 0; it < 7; it++) {
      int r = rb + 64 * it;
      if (r < 400) {
        int sy = r / 20, sx = r - sy * 20;
        int jy = iy0 - 8 + sy, jx = ix0 - 8 + sx;
        int j = (((unsigned)jy < 64u) && ((unsigned)jx < 64u)) ? jy * 64 + jx : 0;
        size_t src = (size_t)j * C_DIM + k0 + seg * 8;
        *(bf16x8*)&WH[r * SROW + seg * 8] = *(const bf16x8*)(fh + src);
        *(bf16x8*)&WL[r * SROW + seg * 8] = *(const bf16x8*)(fl + src);
      }
    }
    __syncthreads();
    bf16x8 aH = *(const bf16x8*)&WH[pr * SROW + kb];
    bf16x8 aL = *(const bf16x8*)&WL[pr * SROW + kb];
    #pragma unroll
    for (int tt = 0; tt < 7; tt++) {
      int row = (t0 + tt) * 16 + l15;
      bf16x8 bH = *(const bf16x8*)&WH[row * SROW + kb];
      bf16x8 bL = *(const bf16x8*)&WL[row * SROW + kb];
      acc[tt] = mfma16(aH, bH, acc[tt]);
      acc[tt] = mfma16(aL, bH, acc[tt]);
      acc[tt] = mfma16(aH, bL, acc[tt]);
    }
  }

  #pragma unroll
  for (int r = 0; r < 4; r++) {
    int r16 = ((lane >> 4) << 2) + r;
    int iy = iy0 + (r16 >> 2), ix = ix0 + (r16 & 3);
    int i = iy * 64 + ix;
    float x2i = x2[i];
    u64 top[8];
    #pragma unroll
    for (int q = 0; q < 8; q++) top[q] = KEY_INF;
    #pragma unroll
    for (int tt = 0; tt < 7; tt++) {
      float d2 = x2i + x2j[tt] - 2.0f * acc[tt][r];
      float fd = sqrtf(fmaxf(d2, 0.0f));
      float dy = (float)(iy - jy_[tt]), dx = (float)(ix - jx_[tt]);
      float sd = sqrtf(dy * dy + dx * dx);
      float comb = 0.7f * sd + 0.3f * fd;
      u64 key = (jj[tt] >= 0)
                    ? (((u64)__float_as_uint(comb) << 12) | (u64)jj[tt])
                    : KEY_INF;
      ins8(key, top);
    }
    #pragma unroll
    for (int d = 1; d < 16; d <<= 1) {
      u64 o[8];
      #pragma unroll
      for (int q = 0; q < 8; q++) o[q] = __shfl_xor(top[q], d);
      merge8(top, o);
    }
    if (l15 == 0) {
      #pragma unroll
      for (int q = 0; q < 8; q++)
        pk[((size_t)w * N_NODES + i) * 8 + q] = top[q];
    }
  }
}

// ---------------- merge 4 partial lists + fused exact fallback + degrees ----------------
__global__ __launch_bounds__(256) void k_topk_merge_fb(
    const u64* __restrict__ pk, const u16* __restrict__ fh,
    const u16* __restrict__ fl, const float* __restrict__ x2,
    int* __restrict__ tk, int* __restrict__ deg) {
  __shared__ int fl_list[256];
  __shared__ int fl_cnt;
  int t = threadIdx.x;
  if (t == 0) fl_cnt = 0;
  __syncthreads();
  int n = blockIdx.x * 256 + t;
  {
    u64 r[8];
    #pragma unroll
    for (int q = 0; q < 8; q++) r[q] = KEY_INF;
    for (int c = 0; c < NCHUNK; c++) {
      const u64* lst = pk + ((size_t)c * N_NODES + n) * 8;
      #pragma unroll
      for (int q = 0; q < 8; q++) {
        u64 key = lst[q];
        if (key >= r[7]) break;
        ins8(key, r);
      }
    }
    float c8 = __uint_as_float((unsigned)(r[7] >> 12));
    if (c8 > 6.28f) {
      int pos = atomicAdd(&fl_cnt, 1);
      fl_list[pos] = n;
    } else {
      #pragma unroll
      for (int o = 0; o < 8; o++) {
        int idx = (int)(r[o] & 0xFFF);
        tk[n * 8 + o] = idx;
        atomicAdd(&deg[idx], 1);
      }
    }
  }
  __syncthreads();
  int nf = fl_cnt;
  int w = t >> 6, lane = t & 63;
  for (int fi = w; fi < nf; fi += 4) {
    int nn = fl_list[fi];
    u64 top[8];
    #pragma unroll
    for (int q = 0; q < 8; q++) top[q] = KEY_INF;
    float x2i = x2[nn];
    int iy = nn >> 6, ix = nn & 63;
    const u16* rh = fh + (size_t)nn * C_DIM;
    const u16* rl = fl + (size_t)nn * C_DIM;
    for (int jb = 0; jb < N_NODES; jb += 64) {
      int j = jb + lane;
      const u16* ch = fh + (size_t)j * C_DIM;
      const u16* cl = fl + (size_t)j * C_DIM;
      float dot = 0.0f;
      for (int k2 = 0; k2 < C_DIM; k2++)
        dot += (bf2f(rh[k2]) + bf2f(rl[k2])) * (bf2f(ch[k2]) + bf2f(cl[k2]));
      float d2 = x2i + x2[j] - 2.0f * dot;
      float fd = sqrtf(fmaxf(d2, 0.0f));
      float dy = (float)(iy - (j >> 6)), dx = (float)(ix - (j & 63));
      float sd = sqrtf(dy * dy + dx * dx);
      float comb = 0.7f * sd + 0.3f * fd;
      ins8(((u64)__float_as_uint(comb) << 12) | (u64)j, top);
    }
    #pragma unroll
    for (int d = 1; d < 64; d <<= 1) {
      u64 o[8];
      #pragma unroll
      for (int q = 0; q < 8; q++) o[q] = __shfl_xor(top[q], d);
      merge8(top, o);
    }
    if (lane == 0) {
      #pragma unroll
      for (int q = 0; q < 8; q++) {
        int idx = (int)(top[q] & 0xFFF);
        tk[nn * 8 + q] = idx;
        atomicAdd(&deg[idx], 1);
      }
    }
  }
}

// ---------------- exclusive scan (4096) + dinv ----------------
__global__ __launch_bounds__(256) void k_scan(const int* __restrict__ deg,
                                              int* __restrict__ offs,
                                              float* __restrict__ dinv) {
  __shared__ int ps[256];
  int t = threadIdx.x;
  int base = t * 16;
  int loc[16]; int s = 0;
  for (int i = 0; i < 16; i++) { int d = deg[base + i]; loc[i] = s; s += d; }
  ps[t] = s;
  __syncthreads();
  for (int d = 1; d < 256; d <<= 1) {
    int add = (t >= d) ? ps[t - d] : 0;
    __syncthreads();
    ps[t] += add;
    __syncthreads();
  }
  int cbase = (t == 0) ? 0 : ps[t - 1];
  for (int i = 0; i < 16; i++) offs[base + i] = cbase + loc[i];
  if (t == 255) offs[N_NODES] = ps[255];
  for (int i = 0; i < 16; i++)
    dinv[base + i] = 1.0f / sqrtf((float)deg[base + i]);
}

// ---------------- CSR fill ----------------
__global__ __launch_bounds__(256) void k_fill(const int* __restrict__ tk,
                                              const int* __restrict__ offs,
                                              int* __restrict__ cnt,
                                              int* __restrict__ insrc) {
  int e = blockIdx.x * 256 + threadIdx.x;
  if (e >= E_TOT) return;
  int i = e >> 3;
  int n = tk[e];
  int pos = offs[n] + atomicAdd(&cnt[n], 1);
  insrc[pos] = i;
}

// ---------------- per-node sort (determinism) ----------------
__global__ __launch_bounds__(256) void k_sort(const int* __restrict__ offs,
                                              int* __restrict__ insrc) {
  int n = blockIdx.x * 256 + threadIdx.x;
  if (n >= N_NODES) return;
  int beg = offs[n], end = offs[n + 1];
  for (int a = beg + 1; a < end; a++) {
    int v = insrc[a]; int p = a;
    while (p > beg && insrc[p - 1] > v) { insrc[p] = insrc[p - 1]; p--; }
    insrc[p] = v;
  }
}

// ---------------- LDS double-buffered bf16 MFMA GEMM via global_load_lds ----------------
// C[M,N] = A[M,K] @ Bt[N,K]^T, 128x128 tile, BK=32, 4 waves 2x2 (64x64 each).
// One barrier per K-step: stage tile k+1 into buf^1 (async DMA) before
// computing tile k from buf; barrier drains vmcnt -> next tile resident.
__device__ __forceinline__ float gelu_f(float x) {
  const float k0 = 0.7978845608028654f;  // sqrt(2/pi)
  float x3 = x * x * x;
  return 0.5f * x * (1.0f + tanhf(k0 * (x + 0.044715f * x3)));
}

template <int EPI>  // 1 = bias+gelu, 3 = plain; bf16 out
__global__ __launch_bounds__(256) void k_gemm_lds(
    const u16* __restrict__ A, const u16* __restrict__ Bt,
    const float* __restrict__ bias, u16* __restrict__ Cout,
    int M, int N, int K) {
  __shared__ u16 As[2 * 128 * 32];
  __shared__ u16 Bs[2 * 128 * 32];
  const int BO = 128 * 32;
  int t = threadIdx.x, lane = t & 63, w = t >> 6;
  int m0 = blockIdx.x * 128;
  int n0 = blockIdx.y * 128;
  int l15 = lane & 15;
  int kg = lane >> 4;
  int wr = (w >> 1) * 64, wc = (w & 1) * 64;

  // staging: wave w covers tile rows w*32 .. w*32+31 (two 16-row chunks);
  // lane l -> row chunkbase + (l>>2), 16B segment (l&3)
  int srow = w * 32 + (lane >> 2);
  int scol = (lane & 3) * 8;
  const u16* gA0 = A + (size_t)(m0 + srow) * K + scol;
  const u16* gA1 = A + (size_t)(m0 + srow + 16) * K + scol;
  int br0 = n0 + srow;      br0 = (br0 < N) ? br0 : 0;
  int br1 = n0 + srow + 16; br1 = (br1 < N) ? br1 : 0;
  const u16* gB0 = Bt + (size_t)br0 * K + scol;
  const u16* gB1 = Bt + (size_t)br1 * K + scol;
  int lo0 = (w * 32) * 32;
  int lo1 = (w * 32 + 16) * 32;

  f32x4 acc[4][4];
  #pragma unroll
  for (int s = 0; s < 4; s++)
    #pragma unroll
    for (int nt = 0; nt < 4; nt++) acc[s][nt] = (f32x4){0.f, 0.f, 0.f, 0.f};

  // prologue: stage tile 0 into buffer 0
  gl_lds16(gA0, &As[lo0]);
  gl_lds16(gA1, &As[lo1]);
  gl_lds16(gB0, &Bs[lo0]);
  gl_lds16(gB1, &Bs[lo1]);
  __syncthreads();

  int NT = K / 32;
  for (int kt = 0; kt < NT; kt++) {
    int cur = (kt & 1) * BO;
    if (kt + 1 < NT) {
      int nb = ((kt + 1) & 1) * BO;
      int ko = (kt + 1) * 32;
      gl_lds16(gA0 + ko, &As[nb + lo0]);
      gl_lds16(gA1 + ko, &As[nb + lo1]);
      gl_lds16(gB0 + ko, &Bs[nb + lo0]);
      gl_lds16(gB1 + ko, &Bs[nb + lo1]);
    }
    bf16x8 a[4], b[4];
    #pragma unroll
    for (int s = 0; s < 4; s++)
      a[s] = *(const bf16x8*)&As[cur + (wr + s * 16 + l15) * 32 + kg * 8];
    #pragma unroll
    for (int nt = 0; nt < 4; nt++)
      b[nt] = *(const bf16x8*)&Bs[cur + (wc + nt * 16 + l15) * 32 + kg * 8];
    #pragma unroll
    for (int s = 0; s < 4; s++)
      #pragma unroll
      for (int nt = 0; nt < 4; nt++)
        acc[s][nt] = mfma16(a[s], b[nt], acc[s][nt]);
    if (kt + 1 < NT) __syncthreads();   // vmcnt drain -> tile kt+1 resident
  }

  #pragma unroll
  for (int s = 0; s < 4; s++) {
    int rbase = m0 + wr + s * 16 + ((lane >> 4) << 2);
    #pragma unroll
    for (int nt = 0; nt < 4; nt++) {
      int n = n0 + wc + nt * 16 + l15;
      if (n >= N) continue;
      float bb = (EPI == 1) ? bias[n] : 0.0f;
      #pragma unroll
      for (int r = 0; r < 4; r++) {
        int m = rbase + r;
        float v = acc[s][nt][r];
        if (EPI == 1) { v += bb; v = gelu_f(v); }
        Cout[(size_t)m * N + n] = f2bf(v);
      }
    }
  }
}

// ---------------- fused MLP tail: unc = sigmoid(gelu(h1@U2+ub2)@U3+ub3) ----------------
__global__ __launch_bounds__(256) void k_mlp2(
    const u16* __restrict__ A, const u16* __restrict__ Bt,
    const float* __restrict__ ub2, const float* __restrict__ U3,
    const float* __restrict__ ub3, float* __restrict__ unc) {
  const int K = 192;
  int t = threadIdx.x, lane = t & 63, w = t >> 6;
  int m0 = blockIdx.x * 128 + w * 32;
  int l15 = lane & 15;
  int kb = (lane >> 4) * 8;

  f32x4 acc[2][6];
  #pragma unroll
  for (int s = 0; s < 2; s++)
    #pragma unroll
    for (int nt = 0; nt < 6; nt++) acc[s][nt] = (f32x4){0.f, 0.f, 0.f, 0.f};

  const u16* ap = A + (size_t)(m0 + l15) * K + kb;
  const u16* bp[6];
  #pragma unroll
  for (int nt = 0; nt < 6; nt++)
    bp[nt] = Bt + (size_t)(nt * 16 + l15) * K + kb;
  const size_t RA = (size_t)16 * K;

  #pragma unroll
  for (int kk = 0; kk < K; kk += 32) {
    bf16x8 a[2], b[6];
    #pragma unroll
    for (int s = 0; s < 2; s++) a[s] = *(const bf16x8*)(ap + s * RA + kk);
    #pragma unroll
    for (int nt = 0; nt < 6; nt++) b[nt] = *(const bf16x8*)(bp[nt] + kk);
    #pragma unroll
    for (int s = 0; s < 2; s++)
      #pragma unroll
      for (int nt = 0; nt < 6; nt++)
        acc[s][nt] = mfma16(a[s], b[nt], acc[s][nt]);
  }

  float ub3v = ub3[0];
  float u3v[6], b2v[6];
  #pragma unroll
  for (int nt = 0; nt < 6; nt++) {
    int col = nt * 16 + l15;
    u3v[nt] = U3[col];
    b2v[nt] = ub2[col];
  }
  #pragma unroll
  for (int s = 0; s < 2; s++) {
    #pragma unroll
    for (int r = 0; r < 4; r++) {
      float part = 0.0f;
      #pragma unroll
      for (int nt = 0; nt < 6; nt++)
        part += gelu_f(acc[s][nt][r] + b2v[nt]) * u3v[nt];
      #pragma unroll
      for (int d = 1; d < 16; d <<= 1) part += __shfl_xor(part, d);
      if (l15 == 0) {
        int m = m0 + s * 16 + ((lane >> 4) << 2) + r;
        unc[m] = 1.0f / (1.0f + expf(-(part + ub3v)));
      }
    }
  }
}

// ---------------- GCN aggregation: 48-lane group = (node, 4-plane half),
// 8 channels/lane via 16B gathers ----------------
__global__ __launch_bounds__(384) void k_gcn_agg(
    const u16* __restrict__ xw, u16* __restrict__ Xb,
    const float* __restrict__ bias, const float* __restrict__ dinv,
    const int* __restrict__ offs, const int* __restrict__ insrc) {
  const size_t PLANE = (size_t)N_NODES * C_DIM;
  int t = threadIdx.x;
  int g = t / 48, l = t % 48;       // 8 groups of 48 lanes
  int slot = blockIdx.x * 8 + g;    // 8192 slots = 4096 nodes x 2 halves
  int n = slot >> 1;
  int hb = (slot & 1) * 4;          // plane base (0 or 4)
  int beg = offs[n], end = offs[n + 1];
  int c0 = l * 8;
  const u16* base = xw + c0 + (size_t)hb * PLANE;

  float a0[8] = {}, a1[8] = {}, a2[8] = {}, a3[8] = {};
  for (int e = beg; e < end; e++) {
    int i = insrc[e];
    float dv = dinv[i];
    const u16* rp = base + (size_t)i * C_DIM;
    bf16x8 v0 = *(const bf16x8*)(rp);
    bf16x8 v1 = *(const bf16x8*)(rp + PLANE);
    bf16x8 v2 = *(const bf16x8*)(rp + 2 * PLANE);
    bf16x8 v3 = *(const bf16x8*)(rp + 3 * PLANE);
    #pragma unroll
    for (int ch = 0; ch < 8; ch++) {
      a0[ch] += dv * bf2f((u16)v0[ch]);
      a1[ch] += dv * bf2f((u16)v1[ch]);
      a2[ch] += dv * bf2f((u16)v2[ch]);
      a3[ch] += dv * bf2f((u16)v3[ch]);
    }
  }

  float dn = dinv[n];
  float bv[8];
  #pragma unroll
  for (int ch = 0; ch < 8; ch++) bv[ch] = bias[c0 + ch];
  size_t ob = (size_t)n * C_DIM + c0 + (size_t)hb * PLANE;
  u16* xp0 = Xb + ob;
  u16* xp1 = Xb + ob + PLANE;
  u16* xp2 = Xb + ob + 2 * PLANE;
  u16* xp3 = Xb + ob + 3 * PLANE;
  bf16x8 xo0 = *(const bf16x8*)xp0, xo1 = *(const bf16x8*)xp1;
  bf16x8 xo2 = *(const bf16x8*)xp2, xo3 = *(const bf16x8*)xp3;
  bf16x8 xn0, xn1, xn2, xn3;
  #pragma unroll
  for (int ch = 0; ch < 8; ch++) {
    xn0[ch] = (short)f2bf(bf2f((u16)xo0[ch]) + fmaxf(dn * a0[ch] + bv[ch], 0.f));
    xn1[ch] = (short)f2bf(bf2f((u16)xo1[ch]) + fmaxf(dn * a1[ch] + bv[ch], 0.f));
    xn2[ch] = (short)f2bf(bf2f((u16)xo2[ch]) + fmaxf(dn * a2[ch] + bv[ch], 0.f));
    xn3[ch] = (short)f2bf(bf2f((u16)xo3[ch]) + fmaxf(dn * a3[ch] + bv[ch], 0.f));
  }
  *(bf16x8*)xp0 = xn0;
  *(bf16x8*)xp1 = xn1;
  *(bf16x8*)xp2 = xn2;
  *(bf16x8*)xp3 = xn3;
}

// ---------------- out = fea * (1 + unc), float4 ----------------
__global__ __launch_bounds__(256) void k_final(
    const float* __restrict__ fea, const float* __restrict__ unc,
    float* __restrict__ out) {
  size_t i4 = (size_t)blockIdx.x * 256 + threadIdx.x;
  size_t idx = i4 * 4;
  if (idx >= (size_t)B_DIM * C_DIM * N_NODES) return;
  int b = (int)(idx / ((size_t)C_DIM * N_NODES));
  int n = (int)(idx & (N_NODES - 1));
  float4 f = *(const float4*)(fea + idx);
  float4 u = *(const float4*)(unc + (size_t)b * N_NODES + n);
  float4 o;
  o.x = f.x * (1.0f + u.x);
  o.y = f.y * (1.0f + u.y);
  o.z = f.z * (1.0f + u.z);
  o.w = f.w * (1.0f + u.w);
  *(float4*)(out + idx) = o;
}

extern "C" void kernel_launch(void* const* d_in, const int* in_sizes, int n_in,
                              void* d_out, int out_size, void* d_ws, size_t ws_size,
                              hipStream_t stream) {
  const float* fea = (const float*)d_in[0];
  const float* W1  = (const float*)d_in[1];
  const float* b1  = (const float*)d_in[2];
  const float* W2  = (const float*)d_in[3];
  const float* b2  = (const float*)d_in[4];
  const float* W3  = (const float*)d_in[5];
  const float* b3  = (const float*)d_in[6];
  const float* U1  = (const float*)d_in[7];
  const float* ub1 = (const float*)d_in[8];
  const float* U2  = (const float*)d_in[9];
  const float* ub2 = (const float*)d_in[10];
  const float* U3  = (const float*)d_in[11];
  const float* ub3 = (const float*)d_in[12];
  float* out = (float*)d_out;

  char* ws = (char*)d_ws;
  u16*   Xb   = (u16*)  (ws + 0);                       // 25165824
  u16*   XWb  = (u16*)  (ws + 25165824);                // 25165824
  u64*   pk   = (u64*)  (ws + 25165824);                // 1048576 (aliases XWb, pre-GEMM)
  u16*   h1b  = (u16*)  (ws + 25165824);                // 12582912 (aliases XWb, post-GCN)
  u16*   fh   = (u16*)  (ws + 50331648);                // 3145728
  u16*   fl   = (u16*)  (ws + 53477376);                // 3145728
  float* x2   = (float*)(ws + 56623104);                // 16384
  int*   tk   = (int*)  (ws + 56639488);                // 131072
  int*   deg  = (int*)  (ws + 56770560);                // 16384
  float* dinv = (float*)(ws + 56786944);                // 16384
  int*   offs = (int*)  (ws + 56803328);                // 16896
  int*   cnt  = (int*)  (ws + 56820224);                // 16384
  int*   insrc= (int*)  (ws + 56836608);                // 131072
  float* unc  = (float*)(ws + 56967680);                // 131072
  u16*   Wt1  = (u16*)  (ws + 57098752);                // 294912
  u16*   Wt2  = (u16*)  (ws + 57393664);                // 294912
  u16*   Wt3  = (u16*)  (ws + 57688576);                // 294912
  u16*   U1t  = (u16*)  (ws + 57983488);                // 147456
  u16*   U2t  = (u16*)  (ws + 58130944);                // 36864

  // 0) weights -> transposed bf16
  k_prep_w<<<2088, 256, 0, stream>>>(W1, W2, W3, U1, U2, Wt1, Wt2, Wt3, U1t, U2t);
  // 1) transpose + mean -> Xb, fh/fl (16B stores)
  k_transpose_mean<<<dim3(N_NODES / 128, C_DIM / 32), dim3(32, 8), 0, stream>>>(
      fea, Xb, fh, fl);
  // 2) norms
  k_x2<<<N_NODES, 64, 0, stream>>>(fh, fl, x2);
  // 3) windowed distance top-8 (LDS-staged, zeroes deg/cnt), fused merge+fb(+deg)
  k_dist_win<<<256, 256, 0, stream>>>(fh, fl, x2, pk, deg, cnt);
  k_topk_merge_fb<<<N_NODES / 256, 256, 0, stream>>>(pk, fh, fl, x2, tk, deg);
  // 4) graph build
  k_scan<<<1, 256, 0, stream>>>(deg, offs, dinv);
  k_fill<<<E_TOT / 256, 256, 0, stream>>>(tk, offs, cnt, insrc);
  k_sort<<<N_NODES / 256, 256, 0, stream>>>(offs, insrc);
  // 5) three GCN layers (double-buffered gl_lds GEMM + batch-fused aggregation)
  const u16* Wl[3] = {Wt1, Wt2, Wt3};
  const float* bl[3] = {b1, b2, b3};
  for (int l = 0; l < 3; l++) {
    k_gemm_lds<3><<<dim3(M_ROWS / 128, 3), 256, 0, stream>>>(
        Xb, Wl[l], nullptr, XWb, M_ROWS, C_DIM, C_DIM);
    k_gcn_agg<<<N_NODES / 4, 384, 0, stream>>>(XWb, Xb, bl[l], dinv, offs, insrc);
  }
  // 6) MLP: h1 = gelu(Xb@U1+ub1) -> bf16; fused tail -> unc
  k_gemm_lds<1><<<dim3(M_ROWS / 128, 2), 256, 0, stream>>>(
      Xb, U1t, ub1, h1b, M_ROWS, 192, C_DIM);
  k_mlp2<<<M_ROWS / 128, 256, 0, stream>>>(h1b, U2t, ub2, U3, ub3, unc);
  // 7) output
  size_t tot = (size_t)B_DIM * C_DIM * N_NODES;
  k_final<<<(tot / 4 + 255) / 256, 256, 0, stream>>>(fea, unc, out);
}

// Round 13
// 270.496 us; speedup vs baseline: 1.4772x; 1.0109x over previous
//
#include <hip/hip_runtime.h>
#include <hip/hip_bf16.h>
#include <math.h>

#define N_NODES 4096
#define C_DIM   384
#define B_DIM   8
#define K_NB    8
#define E_TOT   (N_NODES * K_NB)     // 32768
#define M_ROWS  (B_DIM * N_NODES)    // 32768
#define NCHUNK  4                    // one partial list per wave of the patch block
#define SROW    40                   // dist-win LDS row stride in u16 (32 data + 8 pad)

typedef unsigned long long u64;
typedef unsigned short u16;
typedef __attribute__((ext_vector_type(8))) short bf16x8;
typedef __attribute__((ext_vector_type(4))) float f32x4;
#define KEY_INF 0xFFFFFFFFFFFFFFFFull

__device__ __forceinline__ u16 f2bf(float f) {
  unsigned u = __float_as_uint(f);
  u += 0x7FFFu + ((u >> 16) & 1u);
  return (u16)(u >> 16);
}
__device__ __forceinline__ float bf2f(u16 h) {
  return __uint_as_float((unsigned)h << 16);
}
__device__ __forceinline__ f32x4 mfma16(bf16x8 a, bf16x8 b, f32x4 c) {
  return __builtin_amdgcn_mfma_f32_16x16x32_bf16(a, b, c, 0, 0, 0);
}
// async global->LDS, 16B per lane; LDS dest = wave-uniform base + lane*16
__device__ __forceinline__ void gl_lds16(const u16* gp, u16* lp) {
  __builtin_amdgcn_global_load_lds(
      (const __attribute__((address_space(1))) unsigned int*)gp,
      (__attribute__((address_space(3))) unsigned int*)lp, 16, 0, 0);
}
// bijective XCD swizzle (m157 form): valid when nwg % 8 == 0
__device__ __forceinline__ int xcd_swz(int bid, int nwg) {
  return (bid & 7) * (nwg >> 3) + (bid >> 3);
}

__device__ __forceinline__ void ce(u64& a, u64& b) {
  u64 lo = a < b ? a : b;
  u64 hi = a < b ? b : a;
  a = lo; b = hi;
}
__device__ __forceinline__ void ins8(u64 key, u64 (&r)[8]) {
  if (key < r[7]) {
    #pragma unroll
    for (int i = 0; i < 8; i++) {
      u64 lo = key < r[i] ? key : r[i];
      u64 hi = key < r[i] ? r[i] : key;
      r[i] = lo; key = hi;
    }
  }
}
// merge two ascending sorted-8 lists -> ascending 8 smallest
__device__ __forceinline__ void merge8(u64 (&r)[8], const u64 (&o)[8]) {
  u64 c[8];
  #pragma unroll
  for (int i = 0; i < 8; i++) c[i] = r[i] < o[7 - i] ? r[i] : o[7 - i];
  ce(c[0], c[4]); ce(c[1], c[5]); ce(c[2], c[6]); ce(c[3], c[7]);
  ce(c[0], c[2]); ce(c[1], c[3]); ce(c[4], c[6]); ce(c[5], c[7]);
  ce(c[0], c[1]); ce(c[2], c[3]); ce(c[4], c[5]); ce(c[6], c[7]);
  #pragma unroll
  for (int i = 0; i < 8; i++) r[i] = c[i];
}

// ---------------- weight prep: transpose + bf16 ----------------
__global__ __launch_bounds__(256) void k_prep_w(
    const float* __restrict__ W1, const float* __restrict__ W2,
    const float* __restrict__ W3, const float* __restrict__ U1,
    const float* __restrict__ U2,
    u16* __restrict__ Wt1, u16* __restrict__ Wt2, u16* __restrict__ Wt3,
    u16* __restrict__ U1t, u16* __restrict__ U2t) {
  int idx = blockIdx.x * 256 + threadIdx.x;
  if (idx < 147456) {
    int n = idx / 384, k = idx % 384;
    Wt1[idx] = f2bf(W1[k * 384 + n]);
  } else if (idx < 294912) {
    int i = idx - 147456; int n = i / 384, k = i % 384;
    Wt2[i] = f2bf(W2[k * 384 + n]);
  } else if (idx < 442368) {
    int i = idx - 294912; int n = i / 384, k = i % 384;
    Wt3[i] = f2bf(W3[k * 384 + n]);
  } else if (idx < 516096) {
    int i = idx - 442368; int n = i / 384, k = i % 384;
    U1t[i] = f2bf(U1[k * 192 + n]);
  } else if (idx < 534528) {
    int i = idx - 516096; int n = i / 192, k = i % 192;
    U2t[i] = f2bf(U2[k * 96 + n]);
  }
}

// ---------------- transpose + batch mean -> Xb (bf16) + fh/fl, 16B writes ----------------
__global__ __launch_bounds__(256) void k_transpose_mean(
    const float* __restrict__ fea, u16* __restrict__ Xb,
    u16* __restrict__ fh, u16* __restrict__ fl) {
  __shared__ float tb[32][132];
  __shared__ float ac[32][132];
  int n0 = blockIdx.x * 128, c0 = blockIdx.y * 32;
  int tx = threadIdx.x, ty = threadIdx.y;   // (32,8)
  int flat = ty * 32 + tx;
  int g = flat & 3;            // channel group of 8
  int r2 = flat >> 2;          // row 0..63
  for (int i = ty; i < 32; i += 8) {
    #pragma unroll
    for (int e = 0; e < 4; e++) ac[i][tx * 4 + e] = 0.0f;
  }
  __syncthreads();
  for (int b = 0; b < B_DIM; b++) {
    for (int i = ty; i < 32; i += 8) {
      float4 v = *(const float4*)(fea +
          ((size_t)b * C_DIM + (c0 + i)) * N_NODES + n0 + tx * 4);
      *(float4*)&tb[i][tx * 4] = v;
      ac[i][tx * 4 + 0] += v.x;
      ac[i][tx * 4 + 1] += v.y;
      ac[i][tx * 4 + 2] += v.z;
      ac[i][tx * 4 + 3] += v.w;
    }
    __syncthreads();
    #pragma unroll
    for (int half = 0; half < 2; half++) {
      int r = r2 + 64 * half;
      bf16x8 v;
      #pragma unroll
      for (int cc = 0; cc < 8; cc++) v[cc] = (short)f2bf(tb[g * 8 + cc][r]);
      *(bf16x8*)&Xb[((size_t)b * N_NODES + n0 + r) * C_DIM + c0 + g * 8] = v;
    }
    __syncthreads();
  }
  #pragma unroll
  for (int half = 0; half < 2; half++) {
    int r = r2 + 64 * half;
    bf16x8 vh, vl;
    #pragma unroll
    for (int cc = 0; cc < 8; cc++) {
      float m = ac[g * 8 + cc][r] * 0.125f;
      u16 h = f2bf(m);
      vh[cc] = (short)h;
      vl[cc] = (short)f2bf(m - bf2f(h));
    }
    size_t o = (size_t)(n0 + r) * C_DIM + c0 + g * 8;
    *(bf16x8*)&fh[o] = vh;
    *(bf16x8*)&fl[o] = vl;
  }
}

// ---------------- squared norms (from hi+lo) ----------------
__global__ __launch_bounds__(64) void k_x2(const u16* __restrict__ fh,
                                           const u16* __restrict__ fl,
                                           float* __restrict__ x2) {
  int n = blockIdx.x;
  int lane = threadIdx.x;
  const u16* rh = fh + (size_t)n * C_DIM;
  const u16* rl = fl + (size_t)n * C_DIM;
  float s = 0.0f;
  for (int c = lane; c < C_DIM; c += 64) {
    float v = bf2f(rh[c]) + bf2f(rl[c]);
    s += v * v;
  }
  for (int d = 32; d > 0; d >>= 1) s += __shfl_down(s, d);
  if (lane == 0) x2[n] = s;
}

// ---------------- windowed distance + top-8, LDS-staged per-patch block ----------------
__global__ __launch_bounds__(256) void k_dist_win(
    const u16* __restrict__ fh, const u16* __restrict__ fl,
    const float* __restrict__ x2, u64* __restrict__ pk,
    int* __restrict__ deg, int* __restrict__ cnt) {
  __shared__ u16 WH[400 * SROW];
  __shared__ u16 WL[400 * SROW];
  int t = threadIdx.x;
  int lane = t & 63, w = t >> 6;
  int p = blockIdx.x;
  int py = p >> 4, px = p & 15;
  int iy0 = py * 4, ix0 = px * 4;
  int l15 = lane & 15;
  int kb = (lane >> 4) * 8;

  if (p < 16) { deg[p * 256 + t] = 0; cnt[p * 256 + t] = 0; }

  int t0 = (w == 0) ? 0 : 7 + (w - 1) * 6;
  int nt = w ? 6 : 7;

  int jj[7]; float x2j[7]; int jy_[7], jx_[7];
  #pragma unroll
  for (int tt = 0; tt < 7; tt++) {
    int s = (t0 + tt) * 16 + l15;
    int sy = s / 20, sx = s - sy * 20;
    int jy = iy0 - 8 + sy, jx = ix0 - 8 + sx;
    bool v = (tt < nt) && ((unsigned)jy < 64u) && ((unsigned)jx < 64u);
    jj[tt] = v ? (jy * 64 + jx) : -1;
    jy_[tt] = jy; jx_[tt] = jx;
    x2j[tt] = v ? x2[jy * 64 + jx] : 0.0f;
  }
  int pr = 168 + (l15 >> 2) * 20 + (l15 & 3);

  int seg = t & 3;
  int rb = t >> 2;

  f32x4 acc[7];
  #pragma unroll
  for (int tt = 0; tt < 7; tt++) acc[tt] = (f32x4){0.f, 0.f, 0.f, 0.f};

  for (int kc = 0; kc < 12; kc++) {
    int k0 = kc * 32;
    __syncthreads();
    #pragma unroll
    for (int it = 0; it < 7; it++) {
      int r = rb + 64 * it;
      if (r < 400) {
        int sy = r / 20, sx = r - sy * 20;
        int jy = iy0 - 8 + sy, jx = ix0 - 8 + sx;
        int j = (((unsigned)jy < 64u) && ((unsigned)jx < 64u)) ? jy * 64 + jx : 0;
        size_t src = (size_t)j * C_DIM + k0 + seg * 8;
        *(bf16x8*)&WH[r * SROW + seg * 8] = *(const bf16x8*)(fh + src);
        *(bf16x8*)&WL[r * SROW + seg * 8] = *(const bf16x8*)(fl + src);
      }
    }
    __syncthreads();
    bf16x8 aH = *(const bf16x8*)&WH[pr * SROW + kb];
    bf16x8 aL = *(const bf16x8*)&WL[pr * SROW + kb];
    #pragma unroll
    for (int tt = 0; tt < 7; tt++) {
      int row = (t0 + tt) * 16 + l15;
      bf16x8 bH = *(const bf16x8*)&WH[row * SROW + kb];
      bf16x8 bL = *(const bf16x8*)&WL[row * SROW + kb];
      acc[tt] = mfma16(aH, bH, acc[tt]);
      acc[tt] = mfma16(aL, bH, acc[tt]);
      acc[tt] = mfma16(aH, bL, acc[tt]);
    }
  }

  #pragma unroll
  for (int r = 0; r < 4; r++) {
    int r16 = ((lane >> 4) << 2) + r;
    int iy = iy0 + (r16 >> 2), ix = ix0 + (r16 & 3);
    int i = iy * 64 + ix;
    float x2i = x2[i];
    u64 top[8];
    #pragma unroll
    for (int q = 0; q < 8; q++) top[q] = KEY_INF;
    #pragma unroll
    for (int tt = 0; tt < 7; tt++) {
      float d2 = x2i + x2j[tt] - 2.0f * acc[tt][r];
      float fd = sqrtf(fmaxf(d2, 0.0f));
      float dy = (float)(iy - jy_[tt]), dx = (float)(ix - jx_[tt]);
      float sd = sqrtf(dy * dy + dx * dx);
      float comb = 0.7f * sd + 0.3f * fd;
      u64 key = (jj[tt] >= 0)
                    ? (((u64)__float_as_uint(comb) << 12) | (u64)jj[tt])
                    : KEY_INF;
      ins8(key, top);
    }
    #pragma unroll
    for (int d = 1; d < 16; d <<= 1) {
      u64 o[8];
      #pragma unroll
      for (int q = 0; q < 8; q++) o[q] = __shfl_xor(top[q], d);
      merge8(top, o);
    }
    if (l15 == 0) {
      #pragma unroll
      for (int q = 0; q < 8; q++)
        pk[((size_t)w * N_NODES + i) * 8 + q] = top[q];
    }
  }
}

// ---------------- merge 4 partial lists + fused exact fallback + degrees ----------------
__global__ __launch_bounds__(256) void k_topk_merge_fb(
    const u64* __restrict__ pk, const u16* __restrict__ fh,
    const u16* __restrict__ fl, const float* __restrict__ x2,
    int* __restrict__ tk, int* __restrict__ deg) {
  __shared__ int fl_list[256];
  __shared__ int fl_cnt;
  int t = threadIdx.x;
  if (t == 0) fl_cnt = 0;
  __syncthreads();
  int n = blockIdx.x * 256 + t;
  {
    u64 r[8];
    #pragma unroll
    for (int q = 0; q < 8; q++) r[q] = KEY_INF;
    for (int c = 0; c < NCHUNK; c++) {
      const u64* lst = pk + ((size_t)c * N_NODES + n) * 8;
      #pragma unroll
      for (int q = 0; q < 8; q++) {
        u64 key = lst[q];
        if (key >= r[7]) break;
        ins8(key, r);
      }
    }
    float c8 = __uint_as_float((unsigned)(r[7] >> 12));
    if (c8 > 6.28f) {
      int pos = atomicAdd(&fl_cnt, 1);
      fl_list[pos] = n;
    } else {
      #pragma unroll
      for (int o = 0; o < 8; o++) {
        int idx = (int)(r[o] & 0xFFF);
        tk[n * 8 + o] = idx;
        atomicAdd(&deg[idx], 1);
      }
    }
  }
  __syncthreads();
  int nf = fl_cnt;
  int w = t >> 6, lane = t & 63;
  for (int fi = w; fi < nf; fi += 4) {
    int nn = fl_list[fi];
    u64 top[8];
    #pragma unroll
    for (int q = 0; q < 8; q++) top[q] = KEY_INF;
    float x2i = x2[nn];
    int iy = nn >> 6, ix = nn & 63;
    const u16* rh = fh + (size_t)nn * C_DIM;
    const u16* rl = fl + (size_t)nn * C_DIM;
    for (int jb = 0; jb < N_NODES; jb += 64) {
      int j = jb + lane;
      const u16* ch = fh + (size_t)j * C_DIM;
      const u16* cl = fl + (size_t)j * C_DIM;
      float dot = 0.0f;
      for (int k2 = 0; k2 < C_DIM; k2++)
        dot += (bf2f(rh[k2]) + bf2f(rl[k2])) * (bf2f(ch[k2]) + bf2f(cl[k2]));
      float d2 = x2i + x2[j] - 2.0f * dot;
      float fd = sqrtf(fmaxf(d2, 0.0f));
      float dy = (float)(iy - (j >> 6)), dx = (float)(ix - (j & 63));
      float sd = sqrtf(dy * dy + dx * dx);
      float comb = 0.7f * sd + 0.3f * fd;
      ins8(((u64)__float_as_uint(comb) << 12) | (u64)j, top);
    }
    #pragma unroll
    for (int d = 1; d < 64; d <<= 1) {
      u64 o[8];
      #pragma unroll
      for (int q = 0; q < 8; q++) o[q] = __shfl_xor(top[q], d);
      merge8(top, o);
    }
    if (lane == 0) {
      #pragma unroll
      for (int q = 0; q < 8; q++) {
        int idx = (int)(top[q] & 0xFFF);
        tk[nn * 8 + q] = idx;
        atomicAdd(&deg[idx], 1);
      }
    }
  }
}

// ---------------- exclusive scan (4096) + dinv ----------------
__global__ __launch_bounds__(256) void k_scan(const int* __restrict__ deg,
                                              int* __restrict__ offs,
                                              float* __restrict__ dinv) {
  __shared__ int ps[256];
  int t = threadIdx.x;
  int base = t * 16;
  int loc[16]; int s = 0;
  for (int i = 0; i < 16; i++) { int d = deg[base + i]; loc[i] = s; s += d; }
  ps[t] = s;
  __syncthreads();
  for (int d = 1; d < 256; d <<= 1) {
    int add = (t >= d) ? ps[t - d] : 0;
    __syncthreads();
    ps[t] += add;
    __syncthreads();
  }
  int cbase = (t == 0) ? 0 : ps[t - 1];
  for (int i = 0; i < 16; i++) offs[base + i] = cbase + loc[i];
  if (t == 255) offs[N_NODES] = ps[255];
  for (int i = 0; i < 16; i++)
    dinv[base + i] = 1.0f / sqrtf((float)deg[base + i]);
}

// ---------------- CSR fill ----------------
__global__ __launch_bounds__(256) void k_fill(const int* __restrict__ tk,
                                              const int* __restrict__ offs,
                                              int* __restrict__ cnt,
                                              int* __restrict__ insrc) {
  int e = blockIdx.x * 256 + threadIdx.x;
  if (e >= E_TOT) return;
  int i = e >> 3;
  int n = tk[e];
  int pos = offs[n] + atomicAdd(&cnt[n], 1);
  insrc[pos] = i;
}

// ---------------- per-node sort (determinism) ----------------
__global__ __launch_bounds__(256) void k_sort(const int* __restrict__ offs,
                                              int* __restrict__ insrc) {
  int n = blockIdx.x * 256 + threadIdx.x;
  if (n >= N_NODES) return;
  int beg = offs[n], end = offs[n + 1];
  for (int a = beg + 1; a < end; a++) {
    int v = insrc[a]; int p = a;
    while (p > beg && insrc[p - 1] > v) { insrc[p] = insrc[p - 1]; p--; }
    insrc[p] = v;
  }
}

// ---------------- LDS double-buffered bf16 MFMA GEMM via global_load_lds ----------------
// 1D XCD-swizzled grid, n-tile fastest within an XCD chunk so the nnt blocks
// sharing one A-tile land on the same XCD L2 (A fetched once, not nnt times).
__device__ __forceinline__ float gelu_f(float x) {
  const float k0 = 0.7978845608028654f;  // sqrt(2/pi)
  float x3 = x * x * x;
  return 0.5f * x * (1.0f + tanhf(k0 * (x + 0.044715f * x3)));
}

template <int EPI>  // 1 = bias+gelu, 3 = plain; bf16 out
__global__ __launch_bounds__(256) void k_gemm_lds(
    const u16* __restrict__ A, const u16* __restrict__ Bt,
    const float* __restrict__ bias, u16* __restrict__ Cout,
    int M, int N, int K, int nnt) {
  __shared__ u16 As[2 * 128 * 32];
  __shared__ u16 Bs[2 * 128 * 32];
  const int BO = 128 * 32;
  int wg = xcd_swz(blockIdx.x, gridDim.x);
  int mt = wg / nnt, ntile = wg - mt * nnt;
  int m0 = mt * 128;
  int n0 = ntile * 128;
  int t = threadIdx.x, lane = t & 63, w = t >> 6;
  int l15 = lane & 15;
  int kg = lane >> 4;
  int wr = (w >> 1) * 64, wc = (w & 1) * 64;

  // staging: wave w covers tile rows w*32 .. w*32+31 (two 16-row chunks);
  // lane l -> row chunkbase + (l>>2), 16B segment (l&3)
  int srow = w * 32 + (lane >> 2);
  int scol = (lane & 3) * 8;
  const u16* gA0 = A + (size_t)(m0 + srow) * K + scol;
  const u16* gA1 = A + (size_t)(m0 + srow + 16) * K + scol;
  int br0 = n0 + srow;      br0 = (br0 < N) ? br0 : 0;
  int br1 = n0 + srow + 16; br1 = (br1 < N) ? br1 : 0;
  const u16* gB0 = Bt + (size_t)br0 * K + scol;
  const u16* gB1 = Bt + (size_t)br1 * K + scol;
  int lo0 = (w * 32) * 32;
  int lo1 = (w * 32 + 16) * 32;

  f32x4 acc[4][4];
  #pragma unroll
  for (int s = 0; s < 4; s++)
    #pragma unroll
    for (int nt = 0; nt < 4; nt++) acc[s][nt] = (f32x4){0.f, 0.f, 0.f, 0.f};

  // prologue: stage tile 0 into buffer 0
  gl_lds16(gA0, &As[lo0]);
  gl_lds16(gA1, &As[lo1]);
  gl_lds16(gB0, &Bs[lo0]);
  gl_lds16(gB1, &Bs[lo1]);
  __syncthreads();

  int NT = K / 32;
  for (int kt = 0; kt < NT; kt++) {
    int cur = (kt & 1) * BO;
    if (kt + 1 < NT) {
      int nb = ((kt + 1) & 1) * BO;
      int ko = (kt + 1) * 32;
      gl_lds16(gA0 + ko, &As[nb + lo0]);
      gl_lds16(gA1 + ko, &As[nb + lo1]);
      gl_lds16(gB0 + ko, &Bs[nb + lo0]);
      gl_lds16(gB1 + ko, &Bs[nb + lo1]);
    }
    bf16x8 a[4], b[4];
    #pragma unroll
    for (int s = 0; s < 4; s++)
      a[s] = *(const bf16x8*)&As[cur + (wr + s * 16 + l15) * 32 + kg * 8];
    #pragma unroll
    for (int nt = 0; nt < 4; nt++)
      b[nt] = *(const bf16x8*)&Bs[cur + (wc + nt * 16 + l15) * 32 + kg * 8];
    #pragma unroll
    for (int s = 0; s < 4; s++)
      #pragma unroll
      for (int nt = 0; nt < 4; nt++)
        acc[s][nt] = mfma16(a[s], b[nt], acc[s][nt]);
    if (kt + 1 < NT) __syncthreads();   // vmcnt drain -> tile kt+1 resident
  }

  #pragma unroll
  for (int s = 0; s < 4; s++) {
    int rbase = m0 + wr + s * 16 + ((lane >> 4) << 2);
    #pragma unroll
    for (int nt = 0; nt < 4; nt++) {
      int n = n0 + wc + nt * 16 + l15;
      if (n >= N) continue;
      float bb = (EPI == 1) ? bias[n] : 0.0f;
      #pragma unroll
      for (int r = 0; r < 4; r++) {
        int m = rbase + r;
        float v = acc[s][nt][r];
        if (EPI == 1) { v += bb; v = gelu_f(v); }
        Cout[(size_t)m * N + n] = f2bf(v);
      }
    }
  }
}

// ---------------- fused MLP tail: unc = sigmoid(gelu(h1@U2+ub2)@U3+ub3) ----------------
__global__ __launch_bounds__(256) void k_mlp2(
    const u16* __restrict__ A, const u16* __restrict__ Bt,
    const float* __restrict__ ub2, const float* __restrict__ U3,
    const float* __restrict__ ub3, float* __restrict__ unc) {
  const int K = 192;
  int t = threadIdx.x, lane = t & 63, w = t >> 6;
  int m0 = blockIdx.x * 128 + w * 32;
  int l15 = lane & 15;
  int kb = (lane >> 4) * 8;

  f32x4 acc[2][6];
  #pragma unroll
  for (int s = 0; s < 2; s++)
    #pragma unroll
    for (int nt = 0; nt < 6; nt++) acc[s][nt] = (f32x4){0.f, 0.f, 0.f, 0.f};

  const u16* ap = A + (size_t)(m0 + l15) * K + kb;
  const u16* bp[6];
  #pragma unroll
  for (int nt = 0; nt < 6; nt++)
    bp[nt] = Bt + (size_t)(nt * 16 + l15) * K + kb;
  const size_t RA = (size_t)16 * K;

  #pragma unroll
  for (int kk = 0; kk < K; kk += 32) {
    bf16x8 a[2], b[6];
    #pragma unroll
    for (int s = 0; s < 2; s++) a[s] = *(const bf16x8*)(ap + s * RA + kk);
    #pragma unroll
    for (int nt = 0; nt < 6; nt++) b[nt] = *(const bf16x8*)(bp[nt] + kk);
    #pragma unroll
    for (int s = 0; s < 2; s++)
      #pragma unroll
      for (int nt = 0; nt < 6; nt++)
        acc[s][nt] = mfma16(a[s], b[nt], acc[s][nt]);
  }

  float ub3v = ub3[0];
  float u3v[6], b2v[6];
  #pragma unroll
  for (int nt = 0; nt < 6; nt++) {
    int col = nt * 16 + l15;
    u3v[nt] = U3[col];
    b2v[nt] = ub2[col];
  }
  #pragma unroll
  for (int s = 0; s < 2; s++) {
    #pragma unroll
    for (int r = 0; r < 4; r++) {
      float part = 0.0f;
      #pragma unroll
      for (int nt = 0; nt < 6; nt++)
        part += gelu_f(acc[s][nt][r] + b2v[nt]) * u3v[nt];
      #pragma unroll
      for (int d = 1; d < 16; d <<= 1) part += __shfl_xor(part, d);
      if (l15 == 0) {
        int m = m0 + s * 16 + ((lane >> 4) << 2) + r;
        unc[m] = 1.0f / (1.0f + expf(-(part + ub3v)));
      }
    }
  }
}

// ---------------- GCN aggregation: 48-lane group = (node, 4-plane half),
// XCD-swizzled so each XCD owns a contiguous node range (gather L2 locality) ----------------
__global__ __launch_bounds__(384) void k_gcn_agg(
    const u16* __restrict__ xw, u16* __restrict__ Xb,
    const float* __restrict__ bias, const float* __restrict__ dinv,
    const int* __restrict__ offs, const int* __restrict__ insrc) {
  const size_t PLANE = (size_t)N_NODES * C_DIM;
  int t = threadIdx.x;
  int g = t / 48, l = t % 48;       // 8 groups of 48 lanes
  int blk = xcd_swz(blockIdx.x, gridDim.x);
  int slot = blk * 8 + g;           // 8192 slots = 4096 nodes x 2 halves
  int n = slot >> 1;
  int hb = (slot & 1) * 4;          // plane base (0 or 4)
  int beg = offs[n], end = offs[n + 1];
  int c0 = l * 8;
  const u16* base = xw + c0 + (size_t)hb * PLANE;

  float a0[8] = {}, a1[8] = {}, a2[8] = {}, a3[8] = {};
  for (int e = beg; e < end; e++) {
    int i = insrc[e];
    float dv = dinv[i];
    const u16* rp = base + (size_t)i * C_DIM;
    bf16x8 v0 = *(const bf16x8*)(rp);
    bf16x8 v1 = *(const bf16x8*)(rp + PLANE);
    bf16x8 v2 = *(const bf16x8*)(rp + 2 * PLANE);
    bf16x8 v3 = *(const bf16x8*)(rp + 3 * PLANE);
    #pragma unroll
    for (int ch = 0; ch < 8; ch++) {
      a0[ch] += dv * bf2f((u16)v0[ch]);
      a1[ch] += dv * bf2f((u16)v1[ch]);
      a2[ch] += dv * bf2f((u16)v2[ch]);
      a3[ch] += dv * bf2f((u16)v3[ch]);
    }
  }

  float dn = dinv[n];
  float bv[8];
  #pragma unroll
  for (int ch = 0; ch < 8; ch++) bv[ch] = bias[c0 + ch];
  size_t ob = (size_t)n * C_DIM + c0 + (size_t)hb * PLANE;
  u16* xp0 = Xb + ob;
  u16* xp1 = Xb + ob + PLANE;
  u16* xp2 = Xb + ob + 2 * PLANE;
  u16* xp3 = Xb + ob + 3 * PLANE;
  bf16x8 xo0 = *(const bf16x8*)xp0, xo1 = *(const bf16x8*)xp1;
  bf16x8 xo2 = *(const bf16x8*)xp2, xo3 = *(const bf16x8*)xp3;
  bf16x8 xn0, xn1, xn2, xn3;
  #pragma unroll
  for (int ch = 0; ch < 8; ch++) {
    xn0[ch] = (short)f2bf(bf2f((u16)xo0[ch]) + fmaxf(dn * a0[ch] + bv[ch], 0.f));
    xn1[ch] = (short)f2bf(bf2f((u16)xo1[ch]) + fmaxf(dn * a1[ch] + bv[ch], 0.f));
    xn2[ch] = (short)f2bf(bf2f((u16)xo2[ch]) + fmaxf(dn * a2[ch] + bv[ch], 0.f));
    xn3[ch] = (short)f2bf(bf2f((u16)xo3[ch]) + fmaxf(dn * a3[ch] + bv[ch], 0.f));
  }
  *(bf16x8*)xp0 = xn0;
  *(bf16x8*)xp1 = xn1;
  *(bf16x8*)xp2 = xn2;
  *(bf16x8*)xp3 = xn3;
}

// ---------------- out = fea * (1 + unc), float4 ----------------
__global__ __launch_bounds__(256) void k_final(
    const float* __restrict__ fea, const float* __restrict__ unc,
    float* __restrict__ out) {
  size_t i4 = (size_t)blockIdx.x * 256 + threadIdx.x;
  size_t idx = i4 * 4;
  if (idx >= (size_t)B_DIM * C_DIM * N_NODES) return;
  int b = (int)(idx / ((size_t)C_DIM * N_NODES));
  int n = (int)(idx & (N_NODES - 1));
  float4 f = *(const float4*)(fea + idx);
  float4 u = *(const float4*)(unc + (size_t)b * N_NODES + n);
  float4 o;
  o.x = f.x * (1.0f + u.x);
  o.y = f.y * (1.0f + u.y);
  o.z = f.z * (1.0f + u.z);
  o.w = f.w * (1.0f + u.w);
  *(float4*)(out + idx) = o;
}

extern "C" void kernel_launch(void* const* d_in, const int* in_sizes, int n_in,
                              void* d_out, int out_size, void* d_ws, size_t ws_size,
                              hipStream_t stream) {
  const float* fea = (const float*)d_in[0];
  const float* W1  = (const float*)d_in[1];
  const float* b1  = (const float*)d_in[2];
  const float* W2  = (const float*)d_in[3];
  const float* b2  = (const float*)d_in[4];
  const float* W3  = (const float*)d_in[5];
  const float* b3  = (const float*)d_in[6];
  const float* U1  = (const float*)d_in[7];
  const float* ub1 = (const float*)d_in[8];
  const float* U2  = (const float*)d_in[9];
  const float* ub2 = (const float*)d_in[10];
  const float* U3  = (const float*)d_in[11];
  const float* ub3 = (const float*)d_in[12];
  float* out = (float*)d_out;

  char* ws = (char*)d_ws;
  u16*   Xb   = (u16*)  (ws + 0);                       // 25165824
  u16*   XWb  = (u16*)  (ws + 25165824);                // 25165824
  u64*   pk   = (u64*)  (ws + 25165824);                // 1048576 (aliases XWb, pre-GEMM)
  u16*   h1b  = (u16*)  (ws + 25165824);                // 12582912 (aliases XWb, post-GCN)
  u16*   fh   = (u16*)  (ws + 50331648);                // 3145728
  u16*   fl   = (u16*)  (ws + 53477376);                // 3145728
  float* x2   = (float*)(ws + 56623104);                // 16384
  int*   tk   = (int*)  (ws + 56639488);                // 131072
  int*   deg  = (int*)  (ws + 56770560);                // 16384
  float* dinv = (float*)(ws + 56786944);                // 16384
  int*   offs = (int*)  (ws + 56803328);                // 16896
  int*   cnt  = (int*)  (ws + 56820224);                // 16384
  int*   insrc= (int*)  (ws + 56836608);                // 131072
  float* unc  = (float*)(ws + 56967680);                // 131072
  u16*   Wt1  = (u16*)  (ws + 57098752);                // 294912
  u16*   Wt2  = (u16*)  (ws + 57393664);                // 294912
  u16*   Wt3  = (u16*)  (ws + 57688576);                // 294912
  u16*   U1t  = (u16*)  (ws + 57983488);                // 147456
  u16*   U2t  = (u16*)  (ws + 58130944);                // 36864

  // 0) weights -> transposed bf16
  k_prep_w<<<2088, 256, 0, stream>>>(W1, W2, W3, U1, U2, Wt1, Wt2, Wt3, U1t, U2t);
  // 1) transpose + mean -> Xb, fh/fl (16B stores)
  k_transpose_mean<<<dim3(N_NODES / 128, C_DIM / 32), dim3(32, 8), 0, stream>>>(
      fea, Xb, fh, fl);
  // 2) norms
  k_x2<<<N_NODES, 64, 0, stream>>>(fh, fl, x2);
  // 3) windowed distance top-8 (LDS-staged, zeroes deg/cnt), fused merge+fb(+deg)
  k_dist_win<<<256, 256, 0, stream>>>(fh, fl, x2, pk, deg, cnt);
  k_topk_merge_fb<<<N_NODES / 256, 256, 0, stream>>>(pk, fh, fl, x2, tk, deg);
  // 4) graph build
  k_scan<<<1, 256, 0, stream>>>(deg, offs, dinv);
  k_fill<<<E_TOT / 256, 256, 0, stream>>>(tk, offs, cnt, insrc);
  k_sort<<<N_NODES / 256, 256, 0, stream>>>(offs, insrc);
  // 5) three GCN layers (XCD-swizzled dbuf GEMM + XCD-swizzled aggregation)
  const u16* Wl[3] = {Wt1, Wt2, Wt3};
  const float* bl[3] = {b1, b2, b3};
  for (int l = 0; l < 3; l++) {
    k_gemm_lds<3><<<(M_ROWS / 128) * 3, 256, 0, stream>>>(
        Xb, Wl[l], nullptr, XWb, M_ROWS, C_DIM, C_DIM, 3);
    k_gcn_agg<<<N_NODES / 4, 384, 0, stream>>>(XWb, Xb, bl[l], dinv, offs, insrc);
  }
  // 6) MLP: h1 = gelu(Xb@U1+ub1) -> bf16; fused tail -> unc
  k_gemm_lds<1><<<(M_ROWS / 128) * 2, 256, 0, stream>>>(
      Xb, U1t, ub1, h1b, M_ROWS, 192, C_DIM, 2);
  k_mlp2<<<M_ROWS / 128, 256, 0, stream>>>(h1b, U2t, ub2, U3, ub3, unc);
  // 7) output
  size_t tot = (size_t)B_DIM * C_DIM * N_NODES;
  k_final<<<(tot / 4 + 255) / 256, 256, 0, stream>>>(fea, unc, out);
}